// Round 7
// baseline (275.781 us; speedup 1.0000x reference)
//
#include <hip/hip_runtime.h>
#include <math.h>

#define NB 2
#define NN 1024
#define DD 1024
#define NHH 16
#define HDD 64
#define BTT 20

typedef unsigned short u16;
typedef short bf16x8 __attribute__((ext_vector_type(8)));
typedef float f32x4 __attribute__((ext_vector_type(4)));

#define HMAXL 6.93147180559945f
#define C1 0.18033688011112042f   // 0.125 * log2(e)
#define TLC 0.72134752044448170f  // 0.5 * log2(e)
#define KC  0.072134752044448170f // log2(e) / 20

// ws offsets in floats
#define TRAJ_OFF 0          // unnormalized w, fp32 N*N
#define TL_OFF    1048576   // N*N bf16 -> 524288 float slots
#define DATAB_OFF 1572864
#define WQB_OFF   2621440
#define WKB_OFF   3145728
#define WVB_OFF   3670016
#define WOB_OFF   4194304
#define QB_OFF    4718592
#define KB_OFF    5767168
#define VT_OFF    6815744
#define AOB_OFF   7864320
#define LV_OFF    8912896   // 32768 f
#define HPART_OFF 8945664   // 16*2048 f (ent partials per j-tile)
#define RSP_OFF   8978432   // 4*1024 f (traj row-sum partials per j-tile)

__device__ __forceinline__ float b2f(u16 h) { return __uint_as_float(((unsigned)h) << 16); }
__device__ __forceinline__ u16 f2bf(float f) {
  unsigned u = __float_as_uint(f);
  return (u16)((u + 0x7fffu + ((u >> 16) & 1u)) >> 16);
}
__device__ __forceinline__ void dma16(const void* g, void* l) {
  __builtin_amdgcn_global_load_lds((const __attribute__((address_space(1))) void*)g,
                                   (__attribute__((address_space(3))) void*)l, 16, 0, 0);
}

// ---------------------------------------------------------------------------
// L1: blocks [0,6144) = bf16 conversion (data 2 slices + 4 weights);
//     blocks [6144,6656) = trajA (4 j-tiles x 128 i-tiles), partial row sums.
__global__ __launch_bounds__(256) void prep_kernel(const float* __restrict__ data,
                                                   const float* __restrict__ w0,
                                                   const float* __restrict__ w1,
                                                   const float* __restrict__ w2,
                                                   const float* __restrict__ w3,
                                                   u16* __restrict__ dd,
                                                   u16* __restrict__ d0, u16* __restrict__ d1,
                                                   u16* __restrict__ d2, u16* __restrict__ d3,
                                                   const float* __restrict__ pos,
                                                   const float* __restrict__ quat,
                                                   float* __restrict__ w,
                                                   float* __restrict__ rsp) {
  const int tid = threadIdx.x;
  if (blockIdx.x < 6144) {
    int z = blockIdx.x >> 10, bx = blockIdx.x & 1023;
    const float* s;
    u16* d;
    size_t off = 0;
    if (z < 2) { s = data; d = dd; off = (size_t)z * 1048576; }
    else if (z == 2) { s = w0; d = d0; }
    else if (z == 3) { s = w1; d = d1; }
    else if (z == 4) { s = w2; d = d2; }
    else { s = w3; d = d3; }
    size_t i = off + (size_t)(bx * 256 + tid) * 4;
    float4 v = *(const float4*)(s + i);
    ushort4 o = {f2bf(v.x), f2bf(v.y), f2bf(v.z), f2bf(v.w)};
    *(ushort4*)(d + i) = o;
    return;
  }
  // trajA
  const int t = blockIdx.x - 6144;
  const int jx = t & 3, iy = t >> 2;
  const int j = jx * 256 + tid;
  const int i0 = iy * 8;
  __shared__ float ld[8][BTT][8];
  __shared__ float wredS[4][8];
  if (tid < 8 * BTT) {
    int ii = tid / BTT, bt = tid % BTT;
    const float* pp = pos + ((size_t)bt * NN + i0 + ii) * 3;
    ld[ii][bt][0] = pp[0]; ld[ii][bt][1] = pp[1]; ld[ii][bt][2] = pp[2];
    *(float4*)&ld[ii][bt][4] = *(const float4*)(quat + ((size_t)bt * NN + i0 + ii) * 4);
  }
  __syncthreads();
  float acc[8] = {};
  for (int bt = 0; bt < BTT; ++bt) {
    const float* pj = pos + ((size_t)bt * NN + j) * 3;
    float pjx = pj[0], pjy = pj[1], pjz = pj[2];
    float4 qj = *(const float4*)(quat + ((size_t)bt * NN + j) * 4);
#pragma unroll
    for (int ii = 0; ii < 8; ++ii) {
      float4 pi = *(const float4*)&ld[ii][bt][0];
      float4 qi = *(const float4*)&ld[ii][bt][4];
      float dx = pi.x - pjx, dy = pi.y - pjy, dz = pi.z - pjz;
      float d2 = fmaf(dz, dz, fmaf(dy, dy, dx * dx));
      float dot = fmaf(qi.w, qj.w, fmaf(qi.z, qj.z, fmaf(qi.y, qj.y, qi.x * qj.x)));
      float tq = fmaf(-2.f, fabsf(dot), 2.f);
      acc[ii] += sqrtf(d2) + sqrtf(fmaxf(tq, 0.f));
    }
  }
  const int wv = tid >> 6;
#pragma unroll
  for (int ii = 0; ii < 8; ++ii) {
    float v = exp2f(-acc[ii] * KC);
    w[(size_t)(i0 + ii) * NN + j] = v;
    float s = v;
#pragma unroll
    for (int off = 1; off < 64; off <<= 1) s += __shfl_xor(s, off, 64);
    if ((tid & 63) == 0) wredS[wv][ii] = s;
  }
  __syncthreads();
  if (tid < 8)
    rsp[jx * 1024 + i0 + tid] = wredS[0][tid] + wredS[1][tid] + wredS[2][tid] + wredS[3][tid];
}

// ---------------------------------------------------------------------------
// L2: blocks [0,384) = QKV GEMM (128x128 tile); blocks [384,640) = trajB (4 rows each).
__global__ __launch_bounds__(256) void qkv_trajB_kernel(const u16* __restrict__ Ab,
                                                        const u16* __restrict__ Wq,
                                                        const u16* __restrict__ Wk,
                                                        const u16* __restrict__ Wv,
                                                        const float* __restrict__ bq,
                                                        const float* __restrict__ bk,
                                                        const float* __restrict__ bv,
                                                        u16* __restrict__ Qb,
                                                        u16* __restrict__ Kb,
                                                        u16* __restrict__ VtT,
                                                        const float* __restrict__ wtr,
                                                        const float* __restrict__ rsp,
                                                        u16* __restrict__ tl) {
  const int tid = threadIdx.x;
  __shared__ __align__(16) u16 As[128 * 32];
  __shared__ __align__(16) u16 Bs[128 * 32];
  if (blockIdx.x >= 384) {
    int base = (blockIdx.x - 384) * 4;
#pragma unroll
    for (int r = 0; r < 4; ++r) {
      int i = base + r;
      float inv = TLC / (rsp[i] + rsp[1024 + i] + rsp[2048 + i] + rsp[3072 + i]);
      float4 w4 = *(const float4*)(wtr + (size_t)i * NN + tid * 4);
      ushort4 o = {f2bf(w4.x * inv), f2bf(w4.y * inv), f2bf(w4.z * inv), f2bf(w4.w * inv)};
      *(ushort4*)(tl + (size_t)i * NN + tid * 4) = o;
    }
    return;
  }
  const int z = blockIdx.x >> 7;
  const int rem = blockIdx.x & 127;
  const int bxg = rem & 7, byg = rem >> 3;
  const u16* Wb = z == 0 ? Wq : (z == 1 ? Wk : Wv);
  const float* bias = z == 0 ? bq : (z == 1 ? bk : bv);
  const int w = tid >> 6, l = tid & 63, g = l >> 4, ln = l & 15;
  const int bm = byg << 7, bn = bxg << 7;
  const int srow = w * 16 + (l >> 2);
  const int scol = (l & 3) * 8;
  const u16* Ap0 = Ab + (size_t)(bm + srow) * DD + scol;
  const u16* Ap1 = Ab + (size_t)(bm + 64 + srow) * DD + scol;
  const u16* Bp0 = Wb + (size_t)(bn + srow) * DD + scol;
  const u16* Bp1 = Wb + (size_t)(bn + 64 + srow) * DD + scol;
  u16* dA0 = As + w * 512;
  u16* dA1 = As + 2048 + w * 512;
  u16* dB0 = Bs + w * 512;
  u16* dB1 = Bs + 2048 + w * 512;
  const int mw = (w & 1) * 64, nw = (w >> 1) * 64;
  f32x4 zero4 = {0.f, 0.f, 0.f, 0.f};
  f32x4 acc[4][4];
#pragma unroll
  for (int mt = 0; mt < 4; ++mt)
#pragma unroll
    for (int nt = 0; nt < 4; ++nt) acc[mt][nt] = zero4;
  for (int k0 = 0; k0 < DD; k0 += 32) {
    __syncthreads();
    dma16(Ap0 + k0, dA0); dma16(Ap1 + k0, dA1);
    dma16(Bp0 + k0, dB0); dma16(Bp1 + k0, dB1);
    __syncthreads();
    bf16x8 bfr[4], afr[4];
#pragma unroll
    for (int nt = 0; nt < 4; ++nt)
      bfr[nt] = *(const bf16x8*)&Bs[(nw + nt * 16 + ln) * 32 + g * 8];
#pragma unroll
    for (int mt = 0; mt < 4; ++mt)
      afr[mt] = *(const bf16x8*)&As[(mw + mt * 16 + ln) * 32 + g * 8];
#pragma unroll
    for (int mt = 0; mt < 4; ++mt)
#pragma unroll
      for (int nt = 0; nt < 4; ++nt)
        acc[mt][nt] = __builtin_amdgcn_mfma_f32_16x16x32_bf16(afr[mt], bfr[nt], acc[mt][nt], 0, 0, 0);
  }
#pragma unroll
  for (int nt = 0; nt < 4; ++nt) {
    int n = bn + nw + nt * 16 + ln;
    float bb = bias[n];
    if (z == 2) {
      int row = (((bm >> 10) << 4) + (n >> 6)) * 64 + (n & 63);
#pragma unroll
      for (int mt = 0; mt < 4; ++mt) {
        int tok = (bm & 1023) + mw + mt * 16 + g * 4;
        ushort4 pk = {f2bf(acc[mt][nt][0] + bb), f2bf(acc[mt][nt][1] + bb),
                      f2bf(acc[mt][nt][2] + bb), f2bf(acc[mt][nt][3] + bb)};
        *(ushort4*)(VtT + (size_t)row * NN + tok) = pk;
      }
    } else {
      u16* outp = z == 0 ? Qb : Kb;
#pragma unroll
      for (int mt = 0; mt < 4; ++mt) {
#pragma unroll
        for (int r = 0; r < 4; ++r) {
          int m = bm + mw + mt * 16 + g * 4 + r;
          outp[(size_t)m * DD + n] = f2bf(acc[mt][nt][r] + bb);
        }
      }
    }
  }
}

// ---------------------------------------------------------------------------
// L3: MFMA flash attention per (b,h,i-tile 64), j unrolled x2 (unchanged).
__global__ __launch_bounds__(256) void att_kernel(const u16* __restrict__ Qb,
                                                  const u16* __restrict__ Kb,
                                                  const u16* __restrict__ VtT,
                                                  const u16* __restrict__ tl,
                                                  u16* __restrict__ AOb,
                                                  float* __restrict__ Lv) {
  const int tid = threadIdx.x;
  const int bh = blockIdx.y;
  const int b = bh >> 4, h = bh & 15;
  const int i0 = blockIdx.x << 6;
  const int w = tid >> 6, l = tid & 63, g = l >> 4, ln = l & 15;
  const int wi0 = w * 16;
  __shared__ __align__(16) u16 Qs[64 * 64];
  __shared__ __align__(16) u16 Ks[2][64 * 64];
  __shared__ __align__(16) u16 Vts[2][64 * 64];
  __shared__ __align__(16) u16 Pt[64 * 72];
  __shared__ float lsc[64];
  const int drow0 = w * 16 + (l >> 3), drow1 = drow0 + 8;
  const int dcol = (l & 7) * 8;
  dma16(Qb + ((size_t)(b * NN) + i0 + drow0) * DD + h * HDD + dcol, Qs + (w * 2) * 512);
  dma16(Qb + ((size_t)(b * NN) + i0 + drow1) * DD + h * HDD + dcol, Qs + (w * 2 + 1) * 512);
  const int ig = i0 + wi0 + ln;
  f32x4 zero4 = {0.f, 0.f, 0.f, 0.f};
  f32x4 oacc[4];
#pragma unroll
  for (int nt = 0; nt < 4; ++nt) oacc[nt] = zero4;
  float lacc = 0.f;
  for (int j0 = 0; j0 < NN; j0 += 128) {
    __syncthreads();
#pragma unroll
    for (int u = 0; u < 2; ++u) {
      int jb = j0 + u * 64;
      dma16(Kb + ((size_t)(b * NN) + jb + drow0) * DD + h * HDD + dcol, Ks[u] + (w * 2) * 512);
      dma16(Kb + ((size_t)(b * NN) + jb + drow1) * DD + h * HDD + dcol, Ks[u] + (w * 2 + 1) * 512);
      dma16(VtT + ((size_t)(bh * 64) + drow0) * NN + jb + dcol, Vts[u] + (w * 2) * 512);
      dma16(VtT + ((size_t)(bh * 64) + drow1) * NN + jb + dcol, Vts[u] + (w * 2 + 1) * 512);
    }
    ushort4 tlv[2][4];
#pragma unroll
    for (int u = 0; u < 2; ++u)
#pragma unroll
      for (int jt = 0; jt < 4; ++jt)
        tlv[u][jt] = *(const ushort4*)(tl + (size_t)ig * NN + j0 + u * 64 + jt * 16 + g * 4);
    __syncthreads();
    bf16x8 qf[2];
    qf[0] = *(const bf16x8*)&Qs[(wi0 + ln) * 64 + g * 8];
    qf[1] = *(const bf16x8*)&Qs[(wi0 + ln) * 64 + 32 + g * 8];
#pragma unroll
    for (int u = 0; u < 2; ++u) {
      f32x4 sacc[4];
#pragma unroll
      for (int jt = 0; jt < 4; ++jt) {
        sacc[jt] = zero4;
#pragma unroll
        for (int kc = 0; kc < 2; ++kc) {
          bf16x8 af = *(const bf16x8*)&Ks[u][(jt * 16 + ln) * 64 + kc * 32 + g * 8];
          sacc[jt] = __builtin_amdgcn_mfma_f32_16x16x32_bf16(af, qf[kc], sacc[jt], 0, 0, 0);
        }
      }
#pragma unroll
      for (int jt = 0; jt < 4; ++jt) {
        float e0 = exp2f(sacc[jt][0] * C1 + b2f(tlv[u][jt].x));
        float e1 = exp2f(sacc[jt][1] * C1 + b2f(tlv[u][jt].y));
        float e2 = exp2f(sacc[jt][2] * C1 + b2f(tlv[u][jt].z));
        float e3 = exp2f(sacc[jt][3] * C1 + b2f(tlv[u][jt].w));
        lacc += (e0 + e1) + (e2 + e3);
        ushort4 pk = {f2bf(e0), f2bf(e1), f2bf(e2), f2bf(e3)};
        *(ushort4*)(Pt + (wi0 + ln) * 72 + jt * 16 + g * 4) = pk;
      }
      bf16x8 pf[2];
      pf[0] = *(const bf16x8*)&Pt[(wi0 + ln) * 72 + g * 8];
      pf[1] = *(const bf16x8*)&Pt[(wi0 + ln) * 72 + 32 + g * 8];
#pragma unroll
      for (int nt = 0; nt < 4; ++nt) {
#pragma unroll
        for (int kc = 0; kc < 2; ++kc) {
          bf16x8 vf = *(const bf16x8*)&Vts[u][(nt * 16 + ln) * 64 + kc * 32 + g * 8];
          oacc[nt] = __builtin_amdgcn_mfma_f32_16x16x32_bf16(pf[kc], vf, oacc[nt], 0, 0, 0);
        }
      }
    }
  }
  lacc += __shfl_xor(lacc, 16, 64);
  lacc += __shfl_xor(lacc, 32, 64);
  if (g == 0) {
    Lv[(size_t)bh * NN + i0 + wi0 + ln] = lacc;
    lsc[wi0 + ln] = 1.f / lacc;
  }
  __syncthreads();
#pragma unroll
  for (int nt = 0; nt < 4; ++nt) {
    int d = nt * 16 + ln;
#pragma unroll
    for (int r = 0; r < 4; ++r) {
      int i = wi0 + g * 4 + r;
      float v = oacc[nt][r] * lsc[i];
      AOb[((size_t)(b * NN) + i0 + i) * DD + h * HDD + d] = f2bf(v);
    }
  }
}

// ---------------------------------------------------------------------------
// L4: blocks [0,512) = ent (16 j-tiles x 16 i-tiles x 2 b), writes Hpart[jt][b*N+i];
//     blocks [512,640) = output projection GEMM (128x128 tile, fp32 out).
__global__ __launch_bounds__(256) void ent_o_kernel(const u16* __restrict__ Qb,
                                                    const u16* __restrict__ Kb,
                                                    const u16* __restrict__ tl,
                                                    const float* __restrict__ Lv,
                                                    float* __restrict__ Hp,
                                                    const u16* __restrict__ Ab,
                                                    const u16* __restrict__ Wb,
                                                    const float* __restrict__ bias,
                                                    float* __restrict__ C) {
  const int tid = threadIdx.x;
  // union LDS: ent uses Qs(16384 u16) + Ks(16384 u16) + linv(1024 f = 2048 u16 slots)
  __shared__ __align__(16) u16 smem[16384 * 2 + 2048];
  const int w = tid >> 6, l = tid & 63, g = l >> 4, ln = l & 15;
  if (blockIdx.x >= 512) {
    // ---- gemm_o ----
    const int t = blockIdx.x - 512;
    const int bxg = t & 7, byg = t >> 3;
    u16* As = smem;
    u16* Bs = smem + 4096;
    const int bm = byg << 7, bn = bxg << 7;
    const int srow = w * 16 + (l >> 2);
    const int scol = (l & 3) * 8;
    const u16* Ap0 = Ab + (size_t)(bm + srow) * DD + scol;
    const u16* Ap1 = Ab + (size_t)(bm + 64 + srow) * DD + scol;
    const u16* Bp0 = Wb + (size_t)(bn + srow) * DD + scol;
    const u16* Bp1 = Wb + (size_t)(bn + 64 + srow) * DD + scol;
    u16* dA0 = As + w * 512;
    u16* dA1 = As + 2048 + w * 512;
    u16* dB0 = Bs + w * 512;
    u16* dB1 = Bs + 2048 + w * 512;
    const int mw = (w & 1) * 64, nw = (w >> 1) * 64;
    f32x4 zero4 = {0.f, 0.f, 0.f, 0.f};
    f32x4 acc[4][4];
#pragma unroll
    for (int mt = 0; mt < 4; ++mt)
#pragma unroll
      for (int nt = 0; nt < 4; ++nt) acc[mt][nt] = zero4;
    for (int k0 = 0; k0 < DD; k0 += 32) {
      __syncthreads();
      dma16(Ap0 + k0, dA0); dma16(Ap1 + k0, dA1);
      dma16(Bp0 + k0, dB0); dma16(Bp1 + k0, dB1);
      __syncthreads();
      bf16x8 bfr[4], afr[4];
#pragma unroll
      for (int nt = 0; nt < 4; ++nt)
        bfr[nt] = *(const bf16x8*)&Bs[(nw + nt * 16 + ln) * 32 + g * 8];
#pragma unroll
      for (int mt = 0; mt < 4; ++mt)
        afr[mt] = *(const bf16x8*)&As[(mw + mt * 16 + ln) * 32 + g * 8];
#pragma unroll
      for (int mt = 0; mt < 4; ++mt)
#pragma unroll
        for (int nt = 0; nt < 4; ++nt)
          acc[mt][nt] = __builtin_amdgcn_mfma_f32_16x16x32_bf16(afr[mt], bfr[nt], acc[mt][nt], 0, 0, 0);
    }
#pragma unroll
    for (int nt = 0; nt < 4; ++nt) {
      int n = bn + nw + nt * 16 + ln;
      float bb = bias[n];
#pragma unroll
      for (int mt = 0; mt < 4; ++mt) {
#pragma unroll
        for (int r = 0; r < 4; ++r) {
          int m = bm + mw + mt * 16 + g * 4 + r;
          C[(size_t)m * DD + n] = acc[mt][nt][r] + bb;
        }
      }
    }
    return;
  }
  // ---- ent ----
  const int jx = blockIdx.x & 15;
  const int iy = (blockIdx.x >> 4) & 15;
  const int b = blockIdx.x >> 8;
  const int j0 = jx << 6, i0 = iy << 6;
  const int wi0 = w * 16;
  u16* Qs = smem;
  u16* Ks = smem + 16384;
  float* linv = (float*)(smem + 32768);   // [NHH][64]
#pragma unroll
  for (int rep = 0; rep < 4; ++rep) {
    int idx = tid + (rep << 8);
    int hh = idx >> 6, ii = idx & 63;
    linv[hh * 64 + ii] = 1.f / Lv[((size_t)((b << 4) + hh)) * NN + i0 + ii];
  }
  const int srow = w * 2 + (l >> 5);
  const int scol = (l & 31) * 8;
  const u16* Qg = Qb + ((size_t)(b * NN) + i0 + srow) * DD + scol;
  const u16* Kg = Kb + ((size_t)(b * NN) + j0 + srow) * DD + scol;
  const int ig = i0 + wi0 + ln;
  ushort4 tlv[4];
#pragma unroll
  for (int jt = 0; jt < 4; ++jt)
    tlv[jt] = *(const ushort4*)(tl + (size_t)ig * NN + j0 + jt * 16 + g * 4);
  float P[4][4] = {};
  f32x4 zero4 = {0.f, 0.f, 0.f, 0.f};
  for (int hb = 0; hb < 4; ++hb) {
    __syncthreads();
#pragma unroll
    for (int c = 0; c < 8; ++c) {
      dma16(Qg + (size_t)(c * 8) * DD + hb * 256, Qs + (c * 8 + w * 2) * 256);
      dma16(Kg + (size_t)(c * 8) * DD + hb * 256, Ks + (c * 8 + w * 2) * 256);
    }
    __syncthreads();
#pragma unroll
    for (int hl = 0; hl < 4; ++hl) {
      float li = linv[(hb * 4 + hl) * 64 + wi0 + ln];
      bf16x8 qf[2];
      qf[0] = *(const bf16x8*)&Qs[(wi0 + ln) * 256 + hl * 64 + g * 8];
      qf[1] = *(const bf16x8*)&Qs[(wi0 + ln) * 256 + hl * 64 + 32 + g * 8];
#pragma unroll
      for (int jt = 0; jt < 4; ++jt) {
        f32x4 sacc = zero4;
#pragma unroll
        for (int kc = 0; kc < 2; ++kc) {
          bf16x8 af = *(const bf16x8*)&Ks[(jt * 16 + ln) * 256 + hl * 64 + kc * 32 + g * 8];
          sacc = __builtin_amdgcn_mfma_f32_16x16x32_bf16(af, qf[kc], sacc, 0, 0, 0);
        }
        P[jt][0] += exp2f(sacc[0] * C1 + b2f(tlv[jt].x)) * li;
        P[jt][1] += exp2f(sacc[1] * C1 + b2f(tlv[jt].y)) * li;
        P[jt][2] += exp2f(sacc[2] * C1 + b2f(tlv[jt].z)) * li;
        P[jt][3] += exp2f(sacc[3] * C1 + b2f(tlv[jt].w)) * li;
      }
    }
  }
  float hs = 0.f;
#pragma unroll
  for (int jt = 0; jt < 4; ++jt) {
#pragma unroll
    for (int r = 0; r < 4; ++r) {
      float p = fmaxf(P[jt][r] * (1.f / NHH), 1e-10f);
      hs -= p * logf(p);
    }
  }
  hs += __shfl_xor(hs, 16, 64);
  hs += __shfl_xor(hs, 32, 64);
  if (g == 0) Hp[jx * 2048 + (size_t)b * NN + i0 + wi0 + ln] = hs;
}

// ---------------------------------------------------------------------------
// L5: certainty update, summing the 16 j-tile entropy partials.
__global__ __launch_bounds__(256) void cert_kernel(const float* __restrict__ Hp,
                                                   const float* __restrict__ cert,
                                                   float* __restrict__ outc) {
  int idx = blockIdx.x * 256 + threadIdx.x;
  float H = 0.f;
#pragma unroll
  for (int jt = 0; jt < 16; ++jt) H += Hp[jt * 2048 + idx];
  float sg = 1.f / (1.f + expf(H - HMAXL));
  outc[idx] = fmaxf(cert[idx], sg);
}

// ---------------------------------------------------------------------------
extern "C" void kernel_launch(void* const* d_in, const int* in_sizes, int n_in,
                              void* d_out, int out_size, void* d_ws, size_t ws_size,
                              hipStream_t stream) {
  const float* data      = (const float*)d_in[0];
  const float* traj_pos  = (const float*)d_in[1];
  const float* traj_quat = (const float*)d_in[2];
  const float* certainty = (const float*)d_in[3];
  const float* Wq = (const float*)d_in[4];
  const float* bq = (const float*)d_in[5];
  const float* Wk = (const float*)d_in[6];
  const float* bk = (const float*)d_in[7];
  const float* Wv = (const float*)d_in[8];
  const float* bv = (const float*)d_in[9];
  const float* Wo = (const float*)d_in[10];
  const float* bo = (const float*)d_in[11];

  float* ws = (float*)d_ws;
  float* wtr  = ws + TRAJ_OFF;
  u16* tl    = (u16*)(ws + TL_OFF);
  u16* datab = (u16*)(ws + DATAB_OFF);
  u16* wqb   = (u16*)(ws + WQB_OFF);
  u16* wkb   = (u16*)(ws + WKB_OFF);
  u16* wvb   = (u16*)(ws + WVB_OFF);
  u16* wob   = (u16*)(ws + WOB_OFF);
  u16* Qb    = (u16*)(ws + QB_OFF);
  u16* Kb    = (u16*)(ws + KB_OFF);
  u16* VtT   = (u16*)(ws + VT_OFF);
  u16* AOb   = (u16*)(ws + AOB_OFF);
  float* Lv   = ws + LV_OFF;
  float* Hp   = ws + HPART_OFF;
  float* rsp  = ws + RSP_OFF;
  float* out  = (float*)d_out;
  float* outc = out + (size_t)NB * NN * DD;

  prep_kernel<<<6656, 256, 0, stream>>>(data, Wq, Wk, Wv, Wo,
                                        datab, wqb, wkb, wvb, wob,
                                        traj_pos, traj_quat, wtr, rsp);
  qkv_trajB_kernel<<<640, 256, 0, stream>>>(datab, wqb, wkb, wvb, bq, bk, bv,
                                            Qb, Kb, VtT, wtr, rsp, tl);
  att_kernel<<<dim3(NN / 64, NB * NHH), 256, 0, stream>>>(Qb, Kb, VtT, tl, AOb, Lv);
  ent_o_kernel<<<640, 256, 0, stream>>>(Qb, Kb, tl, Lv, Hp, AOb, wob, bo, out);
  cert_kernel<<<(NB * NN) / 256, 256, 0, stream>>>(Hp, certainty, outc);
}

// Round 8
// 228.712 us; speedup vs baseline: 1.2058x; 1.2058x over previous
//
#include <hip/hip_runtime.h>
#include <math.h>

#define NB 2
#define NN 1024
#define DD 1024
#define NHH 16
#define HDD 64
#define BTT 20

typedef unsigned short u16;
typedef short bf16x8 __attribute__((ext_vector_type(8)));
typedef float f32x4 __attribute__((ext_vector_type(4)));

#define HMAXL 6.93147180559945f
#define C1 0.18033688011112042f   // 0.125 * log2(e)
#define TLC 0.72134752044448170f  // 0.5 * log2(e)
#define KC  0.072134752044448170f // log2(e) / 20

// ws offsets in floats
#define TRAJ_OFF 0          // unnormalized w, fp32 N*N
#define TL_OFF    1048576   // N*N bf16 -> 524288 float slots
#define DATAB_OFF 1572864
#define WQB_OFF   2621440
#define WKB_OFF   3145728
#define WVB_OFF   3670016
#define WOB_OFF   4194304
#define QB_OFF    4718592
#define KB_OFF    5767168
#define VT_OFF    6815744
#define AOB_OFF   7864320
#define LV_OFF    8912896   // 32768 f
#define HPART_OFF 8945664   // 16*2048 f (ent partials per j-tile)
#define RSP_OFF   8978432   // 4*1024 f (traj row-sum partials per j-tile)

__device__ __forceinline__ float b2f(u16 h) { return __uint_as_float(((unsigned)h) << 16); }
__device__ __forceinline__ u16 f2bf(float f) {
  unsigned u = __float_as_uint(f);
  return (u16)((u + 0x7fffu + ((u >> 16) & 1u)) >> 16);
}
__device__ __forceinline__ void dma16(const void* g, void* l) {
  __builtin_amdgcn_global_load_lds((const __attribute__((address_space(1))) void*)g,
                                   (__attribute__((address_space(3))) void*)l, 16, 0, 0);
}

// ---------------------------------------------------------------------------
// bf16 conversion: data (2 z-slices of 1M floats) + 4 weights (1M each).
__global__ __launch_bounds__(256) void conv_kernel(const float* __restrict__ data,
                                                   const float* __restrict__ w0,
                                                   const float* __restrict__ w1,
                                                   const float* __restrict__ w2,
                                                   const float* __restrict__ w3,
                                                   u16* __restrict__ dd,
                                                   u16* __restrict__ d0, u16* __restrict__ d1,
                                                   u16* __restrict__ d2, u16* __restrict__ d3) {
  int z = blockIdx.y;
  const float* s;
  u16* d;
  size_t off = 0;
  if (z < 2) { s = data; d = dd; off = (size_t)z * 1048576; }
  else if (z == 2) { s = w0; d = d0; }
  else if (z == 3) { s = w1; d = d1; }
  else if (z == 4) { s = w2; d = d2; }
  else { s = w3; d = d3; }
  size_t i = off + (size_t)(blockIdx.x * 256 + threadIdx.x) * 4;
  float4 v = *(const float4*)(s + i);
  ushort4 o = {f2bf(v.x), f2bf(v.y), f2bf(v.z), f2bf(v.w)};
  *(ushort4*)(d + i) = o;
}

// ---------------------------------------------------------------------------
// trajA: w[i][j] = exp(-mean_bt(||pi-pj|| + sqrt(2-2|qi.qj|))), partial row sums
// into rsp[jx][i] (no atomics). Standalone kernel (fusion w/ conv caused VGPR
// under-allocation spill pathology -- R7 postmortem).
__global__ __launch_bounds__(256) void trajA_kernel(const float* __restrict__ pos,
                                                    const float* __restrict__ quat,
                                                    float* __restrict__ w,
                                                    float* __restrict__ rsp) {
  const int tid = threadIdx.x;
  const int jx = blockIdx.x;
  const int j = jx * 256 + tid;
  const int i0 = blockIdx.y * 8;
  __shared__ float ld[8][BTT][8];
  __shared__ float wredS[4][8];
  if (tid < 8 * BTT) {
    int ii = tid / BTT, bt = tid % BTT;
    const float* pp = pos + ((size_t)bt * NN + i0 + ii) * 3;
    ld[ii][bt][0] = pp[0]; ld[ii][bt][1] = pp[1]; ld[ii][bt][2] = pp[2];
    *(float4*)&ld[ii][bt][4] = *(const float4*)(quat + ((size_t)bt * NN + i0 + ii) * 4);
  }
  __syncthreads();
  float acc[8] = {};
  for (int bt = 0; bt < BTT; ++bt) {
    const float* pj = pos + ((size_t)bt * NN + j) * 3;
    float pjx = pj[0], pjy = pj[1], pjz = pj[2];
    float4 qj = *(const float4*)(quat + ((size_t)bt * NN + j) * 4);
#pragma unroll
    for (int ii = 0; ii < 8; ++ii) {
      float4 pi = *(const float4*)&ld[ii][bt][0];
      float4 qi = *(const float4*)&ld[ii][bt][4];
      float dx = pi.x - pjx, dy = pi.y - pjy, dz = pi.z - pjz;
      float d2 = fmaf(dz, dz, fmaf(dy, dy, dx * dx));
      float dot = fmaf(qi.w, qj.w, fmaf(qi.z, qj.z, fmaf(qi.y, qj.y, qi.x * qj.x)));
      float tq = fmaf(-2.f, fabsf(dot), 2.f);
      acc[ii] += sqrtf(d2) + sqrtf(fmaxf(tq, 0.f));
    }
  }
  const int wv = tid >> 6;
#pragma unroll
  for (int ii = 0; ii < 8; ++ii) {
    float v = exp2f(-acc[ii] * KC);
    w[(size_t)(i0 + ii) * NN + j] = v;
    float s = v;
#pragma unroll
    for (int off = 1; off < 64; off <<= 1) s += __shfl_xor(s, off, 64);
    if ((tid & 63) == 0) wredS[wv][ii] = s;
  }
  __syncthreads();
  if (tid < 8)
    rsp[jx * 1024 + i0 + tid] = wredS[0][tid] + wredS[1][tid] + wredS[2][tid] + wredS[3][tid];
}

// ---------------------------------------------------------------------------
// blocks [0,384) = QKV GEMM (128x128 tile); blocks [384,640) = trajB (4 rows each).
__global__ __launch_bounds__(256) void qkv_trajB_kernel(const u16* __restrict__ Ab,
                                                        const u16* __restrict__ Wq,
                                                        const u16* __restrict__ Wk,
                                                        const u16* __restrict__ Wv,
                                                        const float* __restrict__ bq,
                                                        const float* __restrict__ bk,
                                                        const float* __restrict__ bv,
                                                        u16* __restrict__ Qb,
                                                        u16* __restrict__ Kb,
                                                        u16* __restrict__ VtT,
                                                        const float* __restrict__ wtr,
                                                        const float* __restrict__ rsp,
                                                        u16* __restrict__ tl) {
  const int tid = threadIdx.x;
  __shared__ __align__(16) u16 As[128 * 32];
  __shared__ __align__(16) u16 Bs[128 * 32];
  if (blockIdx.x >= 384) {
    int base = (blockIdx.x - 384) * 4;
#pragma unroll
    for (int r = 0; r < 4; ++r) {
      int i = base + r;
      float inv = TLC / (rsp[i] + rsp[1024 + i] + rsp[2048 + i] + rsp[3072 + i]);
      float4 w4 = *(const float4*)(wtr + (size_t)i * NN + tid * 4);
      ushort4 o = {f2bf(w4.x * inv), f2bf(w4.y * inv), f2bf(w4.z * inv), f2bf(w4.w * inv)};
      *(ushort4*)(tl + (size_t)i * NN + tid * 4) = o;
    }
    return;
  }
  const int z = blockIdx.x >> 7;
  const int rem = blockIdx.x & 127;
  const int bxg = rem & 7, byg = rem >> 3;
  const u16* Wb = z == 0 ? Wq : (z == 1 ? Wk : Wv);
  const float* bias = z == 0 ? bq : (z == 1 ? bk : bv);
  const int w = tid >> 6, l = tid & 63, g = l >> 4, ln = l & 15;
  const int bm = byg << 7, bn = bxg << 7;
  const int srow = w * 16 + (l >> 2);
  const int scol = (l & 3) * 8;
  const u16* Ap0 = Ab + (size_t)(bm + srow) * DD + scol;
  const u16* Ap1 = Ab + (size_t)(bm + 64 + srow) * DD + scol;
  const u16* Bp0 = Wb + (size_t)(bn + srow) * DD + scol;
  const u16* Bp1 = Wb + (size_t)(bn + 64 + srow) * DD + scol;
  u16* dA0 = As + w * 512;
  u16* dA1 = As + 2048 + w * 512;
  u16* dB0 = Bs + w * 512;
  u16* dB1 = Bs + 2048 + w * 512;
  const int mw = (w & 1) * 64, nw = (w >> 1) * 64;
  f32x4 zero4 = {0.f, 0.f, 0.f, 0.f};
  f32x4 acc[4][4];
#pragma unroll
  for (int mt = 0; mt < 4; ++mt)
#pragma unroll
    for (int nt = 0; nt < 4; ++nt) acc[mt][nt] = zero4;
  for (int k0 = 0; k0 < DD; k0 += 32) {
    __syncthreads();
    dma16(Ap0 + k0, dA0); dma16(Ap1 + k0, dA1);
    dma16(Bp0 + k0, dB0); dma16(Bp1 + k0, dB1);
    __syncthreads();
    bf16x8 bfr[4], afr[4];
#pragma unroll
    for (int nt = 0; nt < 4; ++nt)
      bfr[nt] = *(const bf16x8*)&Bs[(nw + nt * 16 + ln) * 32 + g * 8];
#pragma unroll
    for (int mt = 0; mt < 4; ++mt)
      afr[mt] = *(const bf16x8*)&As[(mw + mt * 16 + ln) * 32 + g * 8];
#pragma unroll
    for (int mt = 0; mt < 4; ++mt)
#pragma unroll
      for (int nt = 0; nt < 4; ++nt)
        acc[mt][nt] = __builtin_amdgcn_mfma_f32_16x16x32_bf16(afr[mt], bfr[nt], acc[mt][nt], 0, 0, 0);
  }
#pragma unroll
  for (int nt = 0; nt < 4; ++nt) {
    int n = bn + nw + nt * 16 + ln;
    float bb = bias[n];
    if (z == 2) {
      int row = (((bm >> 10) << 4) + (n >> 6)) * 64 + (n & 63);
#pragma unroll
      for (int mt = 0; mt < 4; ++mt) {
        int tok = (bm & 1023) + mw + mt * 16 + g * 4;
        ushort4 pk = {f2bf(acc[mt][nt][0] + bb), f2bf(acc[mt][nt][1] + bb),
                      f2bf(acc[mt][nt][2] + bb), f2bf(acc[mt][nt][3] + bb)};
        *(ushort4*)(VtT + (size_t)row * NN + tok) = pk;
      }
    } else {
      u16* outp = z == 0 ? Qb : Kb;
#pragma unroll
      for (int mt = 0; mt < 4; ++mt) {
#pragma unroll
        for (int r = 0; r < 4; ++r) {
          int m = bm + mw + mt * 16 + g * 4 + r;
          outp[(size_t)m * DD + n] = f2bf(acc[mt][nt][r] + bb);
        }
      }
    }
  }
}

// ---------------------------------------------------------------------------
// MFMA flash attention per (b,h,i-tile 64), j unrolled x2. S^T = K Q^T; PV vs Vt.
__global__ __launch_bounds__(256) void att_kernel(const u16* __restrict__ Qb,
                                                  const u16* __restrict__ Kb,
                                                  const u16* __restrict__ VtT,
                                                  const u16* __restrict__ tl,
                                                  u16* __restrict__ AOb,
                                                  float* __restrict__ Lv) {
  const int tid = threadIdx.x;
  const int bh = blockIdx.y;
  const int b = bh >> 4, h = bh & 15;
  const int i0 = blockIdx.x << 6;
  const int w = tid >> 6, l = tid & 63, g = l >> 4, ln = l & 15;
  const int wi0 = w * 16;
  __shared__ __align__(16) u16 Qs[64 * 64];
  __shared__ __align__(16) u16 Ks[2][64 * 64];
  __shared__ __align__(16) u16 Vts[2][64 * 64];
  __shared__ __align__(16) u16 Pt[64 * 72];
  __shared__ float lsc[64];
  const int drow0 = w * 16 + (l >> 3), drow1 = drow0 + 8;
  const int dcol = (l & 7) * 8;
  dma16(Qb + ((size_t)(b * NN) + i0 + drow0) * DD + h * HDD + dcol, Qs + (w * 2) * 512);
  dma16(Qb + ((size_t)(b * NN) + i0 + drow1) * DD + h * HDD + dcol, Qs + (w * 2 + 1) * 512);
  const int ig = i0 + wi0 + ln;
  f32x4 zero4 = {0.f, 0.f, 0.f, 0.f};
  f32x4 oacc[4];
#pragma unroll
  for (int nt = 0; nt < 4; ++nt) oacc[nt] = zero4;
  float lacc = 0.f;
  for (int j0 = 0; j0 < NN; j0 += 128) {
    __syncthreads();
#pragma unroll
    for (int u = 0; u < 2; ++u) {
      int jb = j0 + u * 64;
      dma16(Kb + ((size_t)(b * NN) + jb + drow0) * DD + h * HDD + dcol, Ks[u] + (w * 2) * 512);
      dma16(Kb + ((size_t)(b * NN) + jb + drow1) * DD + h * HDD + dcol, Ks[u] + (w * 2 + 1) * 512);
      dma16(VtT + ((size_t)(bh * 64) + drow0) * NN + jb + dcol, Vts[u] + (w * 2) * 512);
      dma16(VtT + ((size_t)(bh * 64) + drow1) * NN + jb + dcol, Vts[u] + (w * 2 + 1) * 512);
    }
    ushort4 tlv[2][4];
#pragma unroll
    for (int u = 0; u < 2; ++u)
#pragma unroll
      for (int jt = 0; jt < 4; ++jt)
        tlv[u][jt] = *(const ushort4*)(tl + (size_t)ig * NN + j0 + u * 64 + jt * 16 + g * 4);
    __syncthreads();
    bf16x8 qf[2];
    qf[0] = *(const bf16x8*)&Qs[(wi0 + ln) * 64 + g * 8];
    qf[1] = *(const bf16x8*)&Qs[(wi0 + ln) * 64 + 32 + g * 8];
#pragma unroll
    for (int u = 0; u < 2; ++u) {
      f32x4 sacc[4];
#pragma unroll
      for (int jt = 0; jt < 4; ++jt) {
        sacc[jt] = zero4;
#pragma unroll
        for (int kc = 0; kc < 2; ++kc) {
          bf16x8 af = *(const bf16x8*)&Ks[u][(jt * 16 + ln) * 64 + kc * 32 + g * 8];
          sacc[jt] = __builtin_amdgcn_mfma_f32_16x16x32_bf16(af, qf[kc], sacc[jt], 0, 0, 0);
        }
      }
#pragma unroll
      for (int jt = 0; jt < 4; ++jt) {
        float e0 = exp2f(sacc[jt][0] * C1 + b2f(tlv[u][jt].x));
        float e1 = exp2f(sacc[jt][1] * C1 + b2f(tlv[u][jt].y));
        float e2 = exp2f(sacc[jt][2] * C1 + b2f(tlv[u][jt].z));
        float e3 = exp2f(sacc[jt][3] * C1 + b2f(tlv[u][jt].w));
        lacc += (e0 + e1) + (e2 + e3);
        ushort4 pk = {f2bf(e0), f2bf(e1), f2bf(e2), f2bf(e3)};
        *(ushort4*)(Pt + (wi0 + ln) * 72 + jt * 16 + g * 4) = pk;
      }
      bf16x8 pf[2];
      pf[0] = *(const bf16x8*)&Pt[(wi0 + ln) * 72 + g * 8];
      pf[1] = *(const bf16x8*)&Pt[(wi0 + ln) * 72 + 32 + g * 8];
#pragma unroll
      for (int nt = 0; nt < 4; ++nt) {
#pragma unroll
        for (int kc = 0; kc < 2; ++kc) {
          bf16x8 vf = *(const bf16x8*)&Vts[u][(nt * 16 + ln) * 64 + kc * 32 + g * 8];
          oacc[nt] = __builtin_amdgcn_mfma_f32_16x16x32_bf16(pf[kc], vf, oacc[nt], 0, 0, 0);
        }
      }
    }
  }
  lacc += __shfl_xor(lacc, 16, 64);
  lacc += __shfl_xor(lacc, 32, 64);
  if (g == 0) {
    Lv[(size_t)bh * NN + i0 + wi0 + ln] = lacc;
    lsc[wi0 + ln] = 1.f / lacc;
  }
  __syncthreads();
#pragma unroll
  for (int nt = 0; nt < 4; ++nt) {
    int d = nt * 16 + ln;
#pragma unroll
    for (int r = 0; r < 4; ++r) {
      int i = wi0 + g * 4 + r;
      float v = oacc[nt][r] * lsc[i];
      AOb[((size_t)(b * NN) + i0 + i) * DD + h * HDD + d] = f2bf(v);
    }
  }
}

// ---------------------------------------------------------------------------
// blocks [0,512) = ent (16 j x 16 i x 2 b), writes Hpart[jt][b*N+i];
// blocks [512,640) = output projection GEMM (128x128 tile, fp32 out).
__global__ __launch_bounds__(256) void ent_o_kernel(const u16* __restrict__ Qb,
                                                    const u16* __restrict__ Kb,
                                                    const u16* __restrict__ tl,
                                                    const float* __restrict__ Lv,
                                                    float* __restrict__ Hp,
                                                    const u16* __restrict__ Ab,
                                                    const u16* __restrict__ Wb,
                                                    const float* __restrict__ bias,
                                                    float* __restrict__ C) {
  const int tid = threadIdx.x;
  __shared__ __align__(16) u16 smem[16384 * 2 + 2048];
  const int w = tid >> 6, l = tid & 63, g = l >> 4, ln = l & 15;
  if (blockIdx.x >= 512) {
    // ---- gemm_o ----
    const int t = blockIdx.x - 512;
    const int bxg = t & 7, byg = t >> 3;
    u16* As = smem;
    u16* Bs = smem + 4096;
    const int bm = byg << 7, bn = bxg << 7;
    const int srow = w * 16 + (l >> 2);
    const int scol = (l & 3) * 8;
    const u16* Ap0 = Ab + (size_t)(bm + srow) * DD + scol;
    const u16* Ap1 = Ab + (size_t)(bm + 64 + srow) * DD + scol;
    const u16* Bp0 = Wb + (size_t)(bn + srow) * DD + scol;
    const u16* Bp1 = Wb + (size_t)(bn + 64 + srow) * DD + scol;
    u16* dA0 = As + w * 512;
    u16* dA1 = As + 2048 + w * 512;
    u16* dB0 = Bs + w * 512;
    u16* dB1 = Bs + 2048 + w * 512;
    const int mw = (w & 1) * 64, nw = (w >> 1) * 64;
    f32x4 zero4 = {0.f, 0.f, 0.f, 0.f};
    f32x4 acc[4][4];
#pragma unroll
    for (int mt = 0; mt < 4; ++mt)
#pragma unroll
      for (int nt = 0; nt < 4; ++nt) acc[mt][nt] = zero4;
    for (int k0 = 0; k0 < DD; k0 += 32) {
      __syncthreads();
      dma16(Ap0 + k0, dA0); dma16(Ap1 + k0, dA1);
      dma16(Bp0 + k0, dB0); dma16(Bp1 + k0, dB1);
      __syncthreads();
      bf16x8 bfr[4], afr[4];
#pragma unroll
      for (int nt = 0; nt < 4; ++nt)
        bfr[nt] = *(const bf16x8*)&Bs[(nw + nt * 16 + ln) * 32 + g * 8];
#pragma unroll
      for (int mt = 0; mt < 4; ++mt)
        afr[mt] = *(const bf16x8*)&As[(mw + mt * 16 + ln) * 32 + g * 8];
#pragma unroll
      for (int mt = 0; mt < 4; ++mt)
#pragma unroll
        for (int nt = 0; nt < 4; ++nt)
          acc[mt][nt] = __builtin_amdgcn_mfma_f32_16x16x32_bf16(afr[mt], bfr[nt], acc[mt][nt], 0, 0, 0);
    }
#pragma unroll
    for (int nt = 0; nt < 4; ++nt) {
      int n = bn + nw + nt * 16 + ln;
      float bb = bias[n];
#pragma unroll
      for (int mt = 0; mt < 4; ++mt) {
#pragma unroll
        for (int r = 0; r < 4; ++r) {
          int m = bm + mw + mt * 16 + g * 4 + r;
          C[(size_t)m * DD + n] = acc[mt][nt][r] + bb;
        }
      }
    }
    return;
  }
  // ---- ent ----
  const int jx = blockIdx.x & 15;
  const int iy = (blockIdx.x >> 4) & 15;
  const int b = blockIdx.x >> 8;
  const int j0 = jx << 6, i0 = iy << 6;
  const int wi0 = w * 16;
  u16* Qs = smem;
  u16* Ks = smem + 16384;
  float* linv = (float*)(smem + 32768);   // [NHH][64]
#pragma unroll
  for (int rep = 0; rep < 4; ++rep) {
    int idx = tid + (rep << 8);
    int hh = idx >> 6, ii = idx & 63;
    linv[hh * 64 + ii] = 1.f / Lv[((size_t)((b << 4) + hh)) * NN + i0 + ii];
  }
  const int srow = w * 2 + (l >> 5);
  const int scol = (l & 31) * 8;
  const u16* Qg = Qb + ((size_t)(b * NN) + i0 + srow) * DD + scol;
  const u16* Kg = Kb + ((size_t)(b * NN) + j0 + srow) * DD + scol;
  const int ig = i0 + wi0 + ln;
  ushort4 tlv[4];
#pragma unroll
  for (int jt = 0; jt < 4; ++jt)
    tlv[jt] = *(const ushort4*)(tl + (size_t)ig * NN + j0 + jt * 16 + g * 4);
  float P[4][4] = {};
  f32x4 zero4 = {0.f, 0.f, 0.f, 0.f};
  for (int hb = 0; hb < 4; ++hb) {
    __syncthreads();
#pragma unroll
    for (int c = 0; c < 8; ++c) {
      dma16(Qg + (size_t)(c * 8) * DD + hb * 256, Qs + (c * 8 + w * 2) * 256);
      dma16(Kg + (size_t)(c * 8) * DD + hb * 256, Ks + (c * 8 + w * 2) * 256);
    }
    __syncthreads();
#pragma unroll
    for (int hl = 0; hl < 4; ++hl) {
      float li = linv[(hb * 4 + hl) * 64 + wi0 + ln];
      bf16x8 qf[2];
      qf[0] = *(const bf16x8*)&Qs[(wi0 + ln) * 256 + hl * 64 + g * 8];
      qf[1] = *(const bf16x8*)&Qs[(wi0 + ln) * 256 + hl * 64 + 32 + g * 8];
#pragma unroll
      for (int jt = 0; jt < 4; ++jt) {
        f32x4 sacc = zero4;
#pragma unroll
        for (int kc = 0; kc < 2; ++kc) {
          bf16x8 af = *(const bf16x8*)&Ks[(jt * 16 + ln) * 256 + hl * 64 + kc * 32 + g * 8];
          sacc = __builtin_amdgcn_mfma_f32_16x16x32_bf16(af, qf[kc], sacc, 0, 0, 0);
        }
        P[jt][0] += exp2f(sacc[0] * C1 + b2f(tlv[jt].x)) * li;
        P[jt][1] += exp2f(sacc[1] * C1 + b2f(tlv[jt].y)) * li;
        P[jt][2] += exp2f(sacc[2] * C1 + b2f(tlv[jt].z)) * li;
        P[jt][3] += exp2f(sacc[3] * C1 + b2f(tlv[jt].w)) * li;
      }
    }
  }
  float hs = 0.f;
#pragma unroll
  for (int jt = 0; jt < 4; ++jt) {
#pragma unroll
    for (int r = 0; r < 4; ++r) {
      float p = fmaxf(P[jt][r] * (1.f / NHH), 1e-10f);
      hs -= p * logf(p);
    }
  }
  hs += __shfl_xor(hs, 16, 64);
  hs += __shfl_xor(hs, 32, 64);
  if (g == 0) Hp[jx * 2048 + (size_t)b * NN + i0 + wi0 + ln] = hs;
}

// ---------------------------------------------------------------------------
__global__ __launch_bounds__(256) void cert_kernel(const float* __restrict__ Hp,
                                                   const float* __restrict__ cert,
                                                   float* __restrict__ outc) {
  int idx = blockIdx.x * 256 + threadIdx.x;
  float H = 0.f;
#pragma unroll
  for (int jt = 0; jt < 16; ++jt) H += Hp[jt * 2048 + idx];
  float sg = 1.f / (1.f + expf(H - HMAXL));
  outc[idx] = fmaxf(cert[idx], sg);
}

// ---------------------------------------------------------------------------
extern "C" void kernel_launch(void* const* d_in, const int* in_sizes, int n_in,
                              void* d_out, int out_size, void* d_ws, size_t ws_size,
                              hipStream_t stream) {
  const float* data      = (const float*)d_in[0];
  const float* traj_pos  = (const float*)d_in[1];
  const float* traj_quat = (const float*)d_in[2];
  const float* certainty = (const float*)d_in[3];
  const float* Wq = (const float*)d_in[4];
  const float* bq = (const float*)d_in[5];
  const float* Wk = (const float*)d_in[6];
  const float* bk = (const float*)d_in[7];
  const float* Wv = (const float*)d_in[8];
  const float* bv = (const float*)d_in[9];
  const float* Wo = (const float*)d_in[10];
  const float* bo = (const float*)d_in[11];

  float* ws = (float*)d_ws;
  float* wtr  = ws + TRAJ_OFF;
  u16* tl    = (u16*)(ws + TL_OFF);
  u16* datab = (u16*)(ws + DATAB_OFF);
  u16* wqb   = (u16*)(ws + WQB_OFF);
  u16* wkb   = (u16*)(ws + WKB_OFF);
  u16* wvb   = (u16*)(ws + WVB_OFF);
  u16* wob   = (u16*)(ws + WOB_OFF);
  u16* Qb    = (u16*)(ws + QB_OFF);
  u16* Kb    = (u16*)(ws + KB_OFF);
  u16* VtT   = (u16*)(ws + VT_OFF);
  u16* AOb   = (u16*)(ws + AOB_OFF);
  float* Lv   = ws + LV_OFF;
  float* Hp   = ws + HPART_OFF;
  float* rsp  = ws + RSP_OFF;
  float* out  = (float*)d_out;
  float* outc = out + (size_t)NB * NN * DD;

  conv_kernel<<<dim3(1024, 6), 256, 0, stream>>>(data, Wq, Wk, Wv, Wo,
                                                 datab, wqb, wkb, wvb, wob);
  trajA_kernel<<<dim3(4, 128), 256, 0, stream>>>(traj_pos, traj_quat, wtr, rsp);
  qkv_trajB_kernel<<<640, 256, 0, stream>>>(datab, wqb, wkb, wvb, bq, bk, bv,
                                            Qb, Kb, VtT, wtr, rsp, tl);
  att_kernel<<<dim3(NN / 64, NB * NHH), 256, 0, stream>>>(Qb, Kb, VtT, tl, AOb, Lv);
  ent_o_kernel<<<640, 256, 0, stream>>>(Qb, Kb, tl, Lv, Hp, AOb, wob, bo, out);
  cert_kernel<<<(NB * NN) / 256, 256, 0, stream>>>(Hp, certainty, outc);
}

// Round 9
// 221.286 us; speedup vs baseline: 1.2463x; 1.0336x over previous
//
#include <hip/hip_runtime.h>
#include <math.h>

#define NB 2
#define NN 1024
#define DD 1024
#define NHH 16
#define HDD 64
#define BTT 20

typedef unsigned short u16;
typedef short bf16x8 __attribute__((ext_vector_type(8)));
typedef float f32x4 __attribute__((ext_vector_type(4)));

#define HMAXL 6.93147180559945f
#define C1 0.18033688011112042f   // 0.125 * log2(e)
#define TLC 0.72134752044448170f  // 0.5 * log2(e)
#define KC  0.072134752044448170f // log2(e) / 20
#define CH 520                    // padded chunk stride (1024B chunk + 16B pad) in u16

// ws offsets in floats
#define TRAJ_OFF 0          // unnormalized w, fp32 N*N
#define TL_OFF    1048576
#define DATAB_OFF 1572864
#define WQB_OFF   2621440
#define WKB_OFF   3145728
#define WVB_OFF   3670016
#define WOB_OFF   4194304
#define QB_OFF    4718592
#define KB_OFF    5767168
#define VT_OFF    6815744
#define AOB_OFF   7864320
#define LV_OFF    8912896   // 32768 f
#define HPART_OFF 8945664   // 16*2048 f
#define RSP_OFF   8978432   // 4*1024 f

__device__ __forceinline__ float b2f(u16 h) { return __uint_as_float(((unsigned)h) << 16); }
__device__ __forceinline__ u16 f2bf(float f) {
  unsigned u = __float_as_uint(f);
  return (u16)((u + 0x7fffu + ((u >> 16) & 1u)) >> 16);
}
__device__ __forceinline__ void dma16(const void* g, void* l) {
  __builtin_amdgcn_global_load_lds((const __attribute__((address_space(1))) void*)g,
                                   (__attribute__((address_space(3))) void*)l, 16, 0, 0);
}

// ---------------------------------------------------------------------------
__global__ __launch_bounds__(256) void conv_kernel(const float* __restrict__ data,
                                                   const float* __restrict__ w0,
                                                   const float* __restrict__ w1,
                                                   const float* __restrict__ w2,
                                                   const float* __restrict__ w3,
                                                   u16* __restrict__ dd,
                                                   u16* __restrict__ d0, u16* __restrict__ d1,
                                                   u16* __restrict__ d2, u16* __restrict__ d3) {
  int z = blockIdx.y;
  const float* s;
  u16* d;
  size_t off = 0;
  if (z < 2) { s = data; d = dd; off = (size_t)z * 1048576; }
  else if (z == 2) { s = w0; d = d0; }
  else if (z == 3) { s = w1; d = d1; }
  else if (z == 4) { s = w2; d = d2; }
  else { s = w3; d = d3; }
  size_t i = off + (size_t)(blockIdx.x * 256 + threadIdx.x) * 4;
  float4 v = *(const float4*)(s + i);
  ushort4 o = {f2bf(v.x), f2bf(v.y), f2bf(v.z), f2bf(v.w)};
  *(ushort4*)(d + i) = o;
}

// ---------------------------------------------------------------------------
__global__ __launch_bounds__(256) void trajA_kernel(const float* __restrict__ pos,
                                                    const float* __restrict__ quat,
                                                    float* __restrict__ w,
                                                    float* __restrict__ rsp) {
  const int tid = threadIdx.x;
  const int jx = blockIdx.x;
  const int j = jx * 256 + tid;
  const int i0 = blockIdx.y * 8;
  __shared__ float ld[8][BTT][8];
  __shared__ float wredS[4][8];
  if (tid < 8 * BTT) {
    int ii = tid / BTT, bt = tid % BTT;
    const float* pp = pos + ((size_t)bt * NN + i0 + ii) * 3;
    ld[ii][bt][0] = pp[0]; ld[ii][bt][1] = pp[1]; ld[ii][bt][2] = pp[2];
    *(float4*)&ld[ii][bt][4] = *(const float4*)(quat + ((size_t)bt * NN + i0 + ii) * 4);
  }
  __syncthreads();
  float acc[8] = {};
  for (int bt = 0; bt < BTT; ++bt) {
    const float* pj = pos + ((size_t)bt * NN + j) * 3;
    float pjx = pj[0], pjy = pj[1], pjz = pj[2];
    float4 qj = *(const float4*)(quat + ((size_t)bt * NN + j) * 4);
#pragma unroll
    for (int ii = 0; ii < 8; ++ii) {
      float4 pi = *(const float4*)&ld[ii][bt][0];
      float4 qi = *(const float4*)&ld[ii][bt][4];
      float dx = pi.x - pjx, dy = pi.y - pjy, dz = pi.z - pjz;
      float d2 = fmaf(dz, dz, fmaf(dy, dy, dx * dx));
      float dot = fmaf(qi.w, qj.w, fmaf(qi.z, qj.z, fmaf(qi.y, qj.y, qi.x * qj.x)));
      float tq = fmaf(-2.f, fabsf(dot), 2.f);
      acc[ii] += sqrtf(d2) + sqrtf(fmaxf(tq, 0.f));
    }
  }
  const int wv = tid >> 6;
#pragma unroll
  for (int ii = 0; ii < 8; ++ii) {
    float v = exp2f(-acc[ii] * KC);
    w[(size_t)(i0 + ii) * NN + j] = v;
    float s = v;
#pragma unroll
    for (int off = 1; off < 64; off <<= 1) s += __shfl_xor(s, off, 64);
    if ((tid & 63) == 0) wredS[wv][ii] = s;
  }
  __syncthreads();
  if (tid < 8)
    rsp[jx * 1024 + i0 + tid] = wredS[0][tid] + wredS[1][tid] + wredS[2][tid] + wredS[3][tid];
}

// ---------------------------------------------------------------------------
// blocks [0,384) = QKV GEMM (128x128 tile); blocks [384,640) = trajB.
__global__ __launch_bounds__(256) void qkv_trajB_kernel(const u16* __restrict__ Ab,
                                                        const u16* __restrict__ Wq,
                                                        const u16* __restrict__ Wk,
                                                        const u16* __restrict__ Wv,
                                                        const float* __restrict__ bq,
                                                        const float* __restrict__ bk,
                                                        const float* __restrict__ bv,
                                                        u16* __restrict__ Qb,
                                                        u16* __restrict__ Kb,
                                                        u16* __restrict__ VtT,
                                                        const float* __restrict__ wtr,
                                                        const float* __restrict__ rsp,
                                                        u16* __restrict__ tl) {
  const int tid = threadIdx.x;
  __shared__ __align__(16) u16 As[128 * 32];
  __shared__ __align__(16) u16 Bs[128 * 32];
  if (blockIdx.x >= 384) {
    int base = (blockIdx.x - 384) * 4;
#pragma unroll
    for (int r = 0; r < 4; ++r) {
      int i = base + r;
      float inv = TLC / (rsp[i] + rsp[1024 + i] + rsp[2048 + i] + rsp[3072 + i]);
      float4 w4 = *(const float4*)(wtr + (size_t)i * NN + tid * 4);
      ushort4 o = {f2bf(w4.x * inv), f2bf(w4.y * inv), f2bf(w4.z * inv), f2bf(w4.w * inv)};
      *(ushort4*)(tl + (size_t)i * NN + tid * 4) = o;
    }
    return;
  }
  const int z = blockIdx.x >> 7;
  const int rem = blockIdx.x & 127;
  const int bxg = rem & 7, byg = rem >> 3;
  const u16* Wb = z == 0 ? Wq : (z == 1 ? Wk : Wv);
  const float* bias = z == 0 ? bq : (z == 1 ? bk : bv);
  const int w = tid >> 6, l = tid & 63, g = l >> 4, ln = l & 15;
  const int bm = byg << 7, bn = bxg << 7;
  const int srow = w * 16 + (l >> 2);
  const int scol = (l & 3) * 8;
  const u16* Ap0 = Ab + (size_t)(bm + srow) * DD + scol;
  const u16* Ap1 = Ab + (size_t)(bm + 64 + srow) * DD + scol;
  const u16* Bp0 = Wb + (size_t)(bn + srow) * DD + scol;
  const u16* Bp1 = Wb + (size_t)(bn + 64 + srow) * DD + scol;
  u16* dA0 = As + w * 512;
  u16* dA1 = As + 2048 + w * 512;
  u16* dB0 = Bs + w * 512;
  u16* dB1 = Bs + 2048 + w * 512;
  const int mw = (w & 1) * 64, nw = (w >> 1) * 64;
  f32x4 zero4 = {0.f, 0.f, 0.f, 0.f};
  f32x4 acc[4][4];
#pragma unroll
  for (int mt = 0; mt < 4; ++mt)
#pragma unroll
    for (int nt = 0; nt < 4; ++nt) acc[mt][nt] = zero4;
  for (int k0 = 0; k0 < DD; k0 += 32) {
    __syncthreads();
    dma16(Ap0 + k0, dA0); dma16(Ap1 + k0, dA1);
    dma16(Bp0 + k0, dB0); dma16(Bp1 + k0, dB1);
    __syncthreads();
    bf16x8 bfr[4], afr[4];
#pragma unroll
    for (int nt = 0; nt < 4; ++nt)
      bfr[nt] = *(const bf16x8*)&Bs[(nw + nt * 16 + ln) * 32 + g * 8];
#pragma unroll
    for (int mt = 0; mt < 4; ++mt)
      afr[mt] = *(const bf16x8*)&As[(mw + mt * 16 + ln) * 32 + g * 8];
#pragma unroll
    for (int mt = 0; mt < 4; ++mt)
#pragma unroll
      for (int nt = 0; nt < 4; ++nt)
        acc[mt][nt] = __builtin_amdgcn_mfma_f32_16x16x32_bf16(afr[mt], bfr[nt], acc[mt][nt], 0, 0, 0);
  }
#pragma unroll
  for (int nt = 0; nt < 4; ++nt) {
    int n = bn + nw + nt * 16 + ln;
    float bb = bias[n];
    if (z == 2) {
      int row = (((bm >> 10) << 4) + (n >> 6)) * 64 + (n & 63);
#pragma unroll
      for (int mt = 0; mt < 4; ++mt) {
        int tok = (bm & 1023) + mw + mt * 16 + g * 4;
        ushort4 pk = {f2bf(acc[mt][nt][0] + bb), f2bf(acc[mt][nt][1] + bb),
                      f2bf(acc[mt][nt][2] + bb), f2bf(acc[mt][nt][3] + bb)};
        *(ushort4*)(VtT + (size_t)row * NN + tok) = pk;
      }
    } else {
      u16* outp = z == 0 ? Qb : Kb;
#pragma unroll
      for (int mt = 0; mt < 4; ++mt) {
#pragma unroll
        for (int r = 0; r < 4; ++r) {
          int m = bm + mw + mt * 16 + g * 4 + r;
          outp[(size_t)m * DD + n] = f2bf(acc[mt][nt][r] + bb);
        }
      }
    }
  }
}

// ---------------------------------------------------------------------------
// MFMA flash attention. Bank-conflict-free padded chunk LDS layout:
// tile = 64 rows x 64 cols; chunk c (1024B at c*CH u16) holds rows {c, c+8, .., c+56};
// phys(r,d) = (r&7)*CH + (r>>3)*64 + d  -> fragment reads are 2 lanes/bank (free).
__global__ __launch_bounds__(256) void att_kernel(const u16* __restrict__ Qb,
                                                  const u16* __restrict__ Kb,
                                                  const u16* __restrict__ VtT,
                                                  const u16* __restrict__ tl,
                                                  u16* __restrict__ AOb,
                                                  float* __restrict__ Lv) {
  const int tid = threadIdx.x;
  const int bh = blockIdx.y;
  const int b = bh >> 4, h = bh & 15;
  const int i0 = blockIdx.x << 6;
  const int w = tid >> 6, l = tid & 63, g = l >> 4, ln = l & 15;
  const int wi0 = w * 16;
  __shared__ __align__(16) u16 Qs[8 * CH];
  __shared__ __align__(16) u16 Ks[2][8 * CH];
  __shared__ __align__(16) u16 Vts[2][8 * CH];
  __shared__ __align__(16) u16 Pt[64 * 72];
  __shared__ float lsc[64];
  // DMA: wave w stages chunks 2w, 2w+1. Lane l -> logical row c + 8*(l>>3), col (l&7)*8.
  const int c0 = 2 * w, c1 = 2 * w + 1;
  const int rr = 8 * (l >> 3);
  const int dcol = (l & 7) * 8;
  dma16(Qb + ((size_t)(b * NN) + i0 + c0 + rr) * DD + h * HDD + dcol, Qs + c0 * CH);
  dma16(Qb + ((size_t)(b * NN) + i0 + c1 + rr) * DD + h * HDD + dcol, Qs + c1 * CH);
  const int ig = i0 + wi0 + ln;
  // fragment index helpers
  const int lnlo = (ln & 7) * CH;
  const int lnhi = (ln >> 3) * 64;
  f32x4 zero4 = {0.f, 0.f, 0.f, 0.f};
  f32x4 oacc[4];
#pragma unroll
  for (int nt = 0; nt < 4; ++nt) oacc[nt] = zero4;
  float lacc = 0.f;
  for (int j0 = 0; j0 < NN; j0 += 128) {
    __syncthreads();
#pragma unroll
    for (int u = 0; u < 2; ++u) {
      int jb = j0 + u * 64;
      dma16(Kb + ((size_t)(b * NN) + jb + c0 + rr) * DD + h * HDD + dcol, Ks[u] + c0 * CH);
      dma16(Kb + ((size_t)(b * NN) + jb + c1 + rr) * DD + h * HDD + dcol, Ks[u] + c1 * CH);
      dma16(VtT + ((size_t)(bh * 64) + c0 + rr) * NN + jb + dcol, Vts[u] + c0 * CH);
      dma16(VtT + ((size_t)(bh * 64) + c1 + rr) * NN + jb + dcol, Vts[u] + c1 * CH);
    }
    ushort4 tlv[2][4];
#pragma unroll
    for (int u = 0; u < 2; ++u)
#pragma unroll
      for (int jt = 0; jt < 4; ++jt)
        tlv[u][jt] = *(const ushort4*)(tl + (size_t)ig * NN + j0 + u * 64 + jt * 16 + g * 4);
    __syncthreads();
    bf16x8 qf[2];
    qf[0] = *(const bf16x8*)&Qs[lnlo + (2 * w) * 64 + lnhi + g * 8];
    qf[1] = *(const bf16x8*)&Qs[lnlo + (2 * w) * 64 + lnhi + 32 + g * 8];
#pragma unroll
    for (int u = 0; u < 2; ++u) {
      f32x4 sacc[4];
#pragma unroll
      for (int jt = 0; jt < 4; ++jt) {
        sacc[jt] = zero4;
#pragma unroll
        for (int kc = 0; kc < 2; ++kc) {
          bf16x8 af = *(const bf16x8*)&Ks[u][lnlo + (2 * jt) * 64 + lnhi + kc * 32 + g * 8];
          sacc[jt] = __builtin_amdgcn_mfma_f32_16x16x32_bf16(af, qf[kc], sacc[jt], 0, 0, 0);
        }
      }
#pragma unroll
      for (int jt = 0; jt < 4; ++jt) {
        float e0 = exp2f(sacc[jt][0] * C1 + b2f(tlv[u][jt].x));
        float e1 = exp2f(sacc[jt][1] * C1 + b2f(tlv[u][jt].y));
        float e2 = exp2f(sacc[jt][2] * C1 + b2f(tlv[u][jt].z));
        float e3 = exp2f(sacc[jt][3] * C1 + b2f(tlv[u][jt].w));
        lacc += (e0 + e1) + (e2 + e3);
        ushort4 pk = {f2bf(e0), f2bf(e1), f2bf(e2), f2bf(e3)};
        *(ushort4*)(Pt + (wi0 + ln) * 72 + jt * 16 + g * 4) = pk;
      }
      // Pt rows are wave-private -> wave-local LDS ordering suffices.
      bf16x8 pf[2];
      pf[0] = *(const bf16x8*)&Pt[(wi0 + ln) * 72 + g * 8];
      pf[1] = *(const bf16x8*)&Pt[(wi0 + ln) * 72 + 32 + g * 8];
#pragma unroll
      for (int nt = 0; nt < 4; ++nt) {
#pragma unroll
        for (int kc = 0; kc < 2; ++kc) {
          bf16x8 vf = *(const bf16x8*)&Vts[u][lnlo + (2 * nt) * 64 + lnhi + kc * 32 + g * 8];
          oacc[nt] = __builtin_amdgcn_mfma_f32_16x16x32_bf16(pf[kc], vf, oacc[nt], 0, 0, 0);
        }
      }
    }
  }
  lacc += __shfl_xor(lacc, 16, 64);
  lacc += __shfl_xor(lacc, 32, 64);
  if (g == 0) {
    Lv[(size_t)bh * NN + i0 + wi0 + ln] = lacc;
    lsc[wi0 + ln] = 1.f / lacc;
  }
  __syncthreads();
#pragma unroll
  for (int nt = 0; nt < 4; ++nt) {
    int d = nt * 16 + ln;
#pragma unroll
    for (int r = 0; r < 4; ++r) {
      int i = wi0 + g * 4 + r;
      float v = oacc[nt][r] * lsc[i];
      AOb[((size_t)(b * NN) + i0 + i) * DD + h * HDD + d] = f2bf(v);
    }
  }
}

// ---------------------------------------------------------------------------
// blocks [0,512) = ent; blocks [512,640) = output projection GEMM.
// ent LDS: tile = 64 rows x 256 cols (4 heads); chunk c holds rows {2c, 2c+1};
// phys(r,d) = (r>>1)*CH + (r&1)*256 + d -> fragment reads 2 lanes/bank (free).
__global__ __launch_bounds__(256) void ent_o_kernel(const u16* __restrict__ Qb,
                                                    const u16* __restrict__ Kb,
                                                    const u16* __restrict__ tl,
                                                    const float* __restrict__ Lv,
                                                    float* __restrict__ Hp,
                                                    const u16* __restrict__ Ab,
                                                    const u16* __restrict__ Wb,
                                                    const float* __restrict__ bias,
                                                    float* __restrict__ C) {
  const int tid = threadIdx.x;
  __shared__ __align__(16) u16 smem[32 * CH * 2 + 2048];  // Qs(16640) + Ks(16640) + linv
  const int w = tid >> 6, l = tid & 63, g = l >> 4, ln = l & 15;
  if (blockIdx.x >= 512) {
    // ---- gemm_o ----
    const int t = blockIdx.x - 512;
    const int bxg = t & 7, byg = t >> 3;
    u16* As = smem;
    u16* Bs = smem + 4096;
    const int bm = byg << 7, bn = bxg << 7;
    const int srow = w * 16 + (l >> 2);
    const int scol = (l & 3) * 8;
    const u16* Ap0 = Ab + (size_t)(bm + srow) * DD + scol;
    const u16* Ap1 = Ab + (size_t)(bm + 64 + srow) * DD + scol;
    const u16* Bp0 = Wb + (size_t)(bn + srow) * DD + scol;
    const u16* Bp1 = Wb + (size_t)(bn + 64 + srow) * DD + scol;
    u16* dA0 = As + w * 512;
    u16* dA1 = As + 2048 + w * 512;
    u16* dB0 = Bs + w * 512;
    u16* dB1 = Bs + 2048 + w * 512;
    const int mw = (w & 1) * 64, nw = (w >> 1) * 64;
    f32x4 zero4 = {0.f, 0.f, 0.f, 0.f};
    f32x4 acc[4][4];
#pragma unroll
    for (int mt = 0; mt < 4; ++mt)
#pragma unroll
      for (int nt = 0; nt < 4; ++nt) acc[mt][nt] = zero4;
    for (int k0 = 0; k0 < DD; k0 += 32) {
      __syncthreads();
      dma16(Ap0 + k0, dA0); dma16(Ap1 + k0, dA1);
      dma16(Bp0 + k0, dB0); dma16(Bp1 + k0, dB1);
      __syncthreads();
      bf16x8 bfr[4], afr[4];
#pragma unroll
      for (int nt = 0; nt < 4; ++nt)
        bfr[nt] = *(const bf16x8*)&Bs[(nw + nt * 16 + ln) * 32 + g * 8];
#pragma unroll
      for (int mt = 0; mt < 4; ++mt)
        afr[mt] = *(const bf16x8*)&As[(mw + mt * 16 + ln) * 32 + g * 8];
#pragma unroll
      for (int mt = 0; mt < 4; ++mt)
#pragma unroll
        for (int nt = 0; nt < 4; ++nt)
          acc[mt][nt] = __builtin_amdgcn_mfma_f32_16x16x32_bf16(afr[mt], bfr[nt], acc[mt][nt], 0, 0, 0);
    }
#pragma unroll
    for (int nt = 0; nt < 4; ++nt) {
      int n = bn + nw + nt * 16 + ln;
      float bb = bias[n];
#pragma unroll
      for (int mt = 0; mt < 4; ++mt) {
#pragma unroll
        for (int r = 0; r < 4; ++r) {
          int m = bm + mw + mt * 16 + g * 4 + r;
          C[(size_t)m * DD + n] = acc[mt][nt][r] + bb;
        }
      }
    }
    return;
  }
  // ---- ent ----
  const int jx = blockIdx.x & 15;
  const int iy = (blockIdx.x >> 4) & 15;
  const int b = blockIdx.x >> 8;
  const int j0 = jx << 6, i0 = iy << 6;
  const int wi0 = w * 16;
  u16* Qs = smem;
  u16* Ks = smem + 32 * CH;
  float* linv = (float*)(smem + 64 * CH);   // [NHH][64]
#pragma unroll
  for (int rep = 0; rep < 4; ++rep) {
    int idx = tid + (rep << 8);
    int hh = idx >> 6, ii = idx & 63;
    linv[hh * 64 + ii] = 1.f / Lv[((size_t)((b << 4) + hh)) * NN + i0 + ii];
  }
  // DMA: wave w stages chunks 8w..8w+7; chunk c holds rows 2c,2c+1.
  // Lane l -> row 2c + (l>>5), col (l&31)*8 within the 4-head slab.
  const int rlo = l >> 5;
  const int scol = (l & 31) * 8;
  const int ig = i0 + wi0 + ln;
  const int elo = (ln >> 1) * CH;
  const int ehi = (ln & 1) * 256;
  ushort4 tlv[4];
#pragma unroll
  for (int jt = 0; jt < 4; ++jt)
    tlv[jt] = *(const ushort4*)(tl + (size_t)ig * NN + j0 + jt * 16 + g * 4);
  float P[4][4] = {};
  f32x4 zero4 = {0.f, 0.f, 0.f, 0.f};
  for (int hb = 0; hb < 4; ++hb) {
    __syncthreads();
#pragma unroll
    for (int cc = 0; cc < 8; ++cc) {
      int c = w * 8 + cc;
      dma16(Qb + ((size_t)(b * NN) + i0 + 2 * c + rlo) * DD + hb * 256 + scol, Qs + c * CH);
      dma16(Kb + ((size_t)(b * NN) + j0 + 2 * c + rlo) * DD + hb * 256 + scol, Ks + c * CH);
    }
    __syncthreads();
#pragma unroll
    for (int hl = 0; hl < 4; ++hl) {
      float li = linv[(hb * 4 + hl) * 64 + wi0 + ln];
      bf16x8 qf[2];
      qf[0] = *(const bf16x8*)&Qs[(w * 8) * CH + elo + ehi + hl * 64 + g * 8];
      qf[1] = *(const bf16x8*)&Qs[(w * 8) * CH + elo + ehi + hl * 64 + 32 + g * 8];
#pragma unroll
      for (int jt = 0; jt < 4; ++jt) {
        f32x4 sacc = zero4;
#pragma unroll
        for (int kc = 0; kc < 2; ++kc) {
          bf16x8 af = *(const bf16x8*)&Ks[(jt * 8) * CH + elo + ehi + hl * 64 + kc * 32 + g * 8];
          sacc = __builtin_amdgcn_mfma_f32_16x16x32_bf16(af, qf[kc], sacc, 0, 0, 0);
        }
        P[jt][0] += exp2f(sacc[0] * C1 + b2f(tlv[jt].x)) * li;
        P[jt][1] += exp2f(sacc[1] * C1 + b2f(tlv[jt].y)) * li;
        P[jt][2] += exp2f(sacc[2] * C1 + b2f(tlv[jt].z)) * li;
        P[jt][3] += exp2f(sacc[3] * C1 + b2f(tlv[jt].w)) * li;
      }
    }
  }
  float hs = 0.f;
#pragma unroll
  for (int jt = 0; jt < 4; ++jt) {
#pragma unroll
    for (int r = 0; r < 4; ++r) {
      float p = fmaxf(P[jt][r] * (1.f / NHH), 1e-10f);
      hs -= p * logf(p);
    }
  }
  hs += __shfl_xor(hs, 16, 64);
  hs += __shfl_xor(hs, 32, 64);
  if (g == 0) Hp[jx * 2048 + (size_t)b * NN + i0 + wi0 + ln] = hs;
}

// ---------------------------------------------------------------------------
__global__ __launch_bounds__(256) void cert_kernel(const float* __restrict__ Hp,
                                                   const float* __restrict__ cert,
                                                   float* __restrict__ outc) {
  int idx = blockIdx.x * 256 + threadIdx.x;
  float H = 0.f;
#pragma unroll
  for (int jt = 0; jt < 16; ++jt) H += Hp[jt * 2048 + idx];
  float sg = 1.f / (1.f + expf(H - HMAXL));
  outc[idx] = fmaxf(cert[idx], sg);
}

// ---------------------------------------------------------------------------
extern "C" void kernel_launch(void* const* d_in, const int* in_sizes, int n_in,
                              void* d_out, int out_size, void* d_ws, size_t ws_size,
                              hipStream_t stream) {
  const float* data      = (const float*)d_in[0];
  const float* traj_pos  = (const float*)d_in[1];
  const float* traj_quat = (const float*)d_in[2];
  const float* certainty = (const float*)d_in[3];
  const float* Wq = (const float*)d_in[4];
  const float* bq = (const float*)d_in[5];
  const float* Wk = (const float*)d_in[6];
  const float* bk = (const float*)d_in[7];
  const float* Wv = (const float*)d_in[8];
  const float* bv = (const float*)d_in[9];
  const float* Wo = (const float*)d_in[10];
  const float* bo = (const float*)d_in[11];

  float* ws = (float*)d_ws;
  float* wtr  = ws + TRAJ_OFF;
  u16* tl    = (u16*)(ws + TL_OFF);
  u16* datab = (u16*)(ws + DATAB_OFF);
  u16* wqb   = (u16*)(ws + WQB_OFF);
  u16* wkb   = (u16*)(ws + WKB_OFF);
  u16* wvb   = (u16*)(ws + WVB_OFF);
  u16* wob   = (u16*)(ws + WOB_OFF);
  u16* Qb    = (u16*)(ws + QB_OFF);
  u16* Kb    = (u16*)(ws + KB_OFF);
  u16* VtT   = (u16*)(ws + VT_OFF);
  u16* AOb   = (u16*)(ws + AOB_OFF);
  float* Lv   = ws + LV_OFF;
  float* Hp   = ws + HPART_OFF;
  float* rsp  = ws + RSP_OFF;
  float* out  = (float*)d_out;
  float* outc = out + (size_t)NB * NN * DD;

  conv_kernel<<<dim3(1024, 6), 256, 0, stream>>>(data, Wq, Wk, Wv, Wo,
                                                 datab, wqb, wkb, wvb, wob);
  trajA_kernel<<<dim3(4, 128), 256, 0, stream>>>(traj_pos, traj_quat, wtr, rsp);
  qkv_trajB_kernel<<<640, 256, 0, stream>>>(datab, wqb, wkb, wvb, bq, bk, bv,
                                            Qb, Kb, VtT, wtr, rsp, tl);
  att_kernel<<<dim3(NN / 64, NB * NHH), 256, 0, stream>>>(Qb, Kb, VtT, tl, AOb, Lv);
  ent_o_kernel<<<640, 256, 0, stream>>>(Qb, Kb, tl, Lv, Hp, AOb, wob, bo, out);
  cert_kernel<<<(NB * NN) / 256, 256, 0, stream>>>(Hp, certainty, outc);
}

// Round 10
// 221.084 us; speedup vs baseline: 1.2474x; 1.0009x over previous
//
#include <hip/hip_runtime.h>
#include <math.h>

#define NB 2
#define NN 1024
#define DD 1024
#define NHH 16
#define HDD 64
#define BTT 20

typedef unsigned short u16;
typedef short bf16x8 __attribute__((ext_vector_type(8)));
typedef float f32x4 __attribute__((ext_vector_type(4)));

#define HMAXL 6.93147180559945f
#define C1 0.18033688011112042f   // 0.125 * log2(e)
#define TLC 0.72134752044448170f  // 0.5 * log2(e)
#define KC  0.072134752044448170f // log2(e) / 20
#define CH 520                    // padded chunk stride (1024B chunk + 16B pad) in u16

// ws offsets in floats
#define TRAJ_OFF 0          // unnormalized w, fp32 N*N
#define TL_OFF    1048576
#define DATAB_OFF 1572864
#define WQB_OFF   2621440
#define WKB_OFF   3145728
#define WVB_OFF   3670016
#define WOB_OFF   4194304
#define QB_OFF    4718592
#define KB_OFF    5767168
#define VT_OFF    6815744
#define AOB_OFF   7864320
#define LV_OFF    8912896   // 32768 f
#define HPART_OFF 8945664   // 16*2048 f
#define RSP_OFF   8978432   // 4*1024 f

__device__ __forceinline__ float b2f(u16 h) { return __uint_as_float(((unsigned)h) << 16); }
__device__ __forceinline__ u16 f2bf(float f) {
  unsigned u = __float_as_uint(f);
  return (u16)((u + 0x7fffu + ((u >> 16) & 1u)) >> 16);
}
__device__ __forceinline__ void dma16(const void* g, void* l) {
  __builtin_amdgcn_global_load_lds((const __attribute__((address_space(1))) void*)g,
                                   (__attribute__((address_space(3))) void*)l, 16, 0, 0);
}

// ---------------------------------------------------------------------------
__global__ __launch_bounds__(256) void conv_kernel(const float* __restrict__ data,
                                                   const float* __restrict__ w0,
                                                   const float* __restrict__ w1,
                                                   const float* __restrict__ w2,
                                                   const float* __restrict__ w3,
                                                   u16* __restrict__ dd,
                                                   u16* __restrict__ d0, u16* __restrict__ d1,
                                                   u16* __restrict__ d2, u16* __restrict__ d3) {
  int z = blockIdx.y;
  const float* s;
  u16* d;
  size_t off = 0;
  if (z < 2) { s = data; d = dd; off = (size_t)z * 1048576; }
  else if (z == 2) { s = w0; d = d0; }
  else if (z == 3) { s = w1; d = d1; }
  else if (z == 4) { s = w2; d = d2; }
  else { s = w3; d = d3; }
  size_t i = off + (size_t)(blockIdx.x * 256 + threadIdx.x) * 4;
  float4 v = *(const float4*)(s + i);
  ushort4 o = {f2bf(v.x), f2bf(v.y), f2bf(v.z), f2bf(v.w)};
  *(ushort4*)(d + i) = o;
}

// ---------------------------------------------------------------------------
__global__ __launch_bounds__(256) void trajA_kernel(const float* __restrict__ pos,
                                                    const float* __restrict__ quat,
                                                    float* __restrict__ w,
                                                    float* __restrict__ rsp) {
  const int tid = threadIdx.x;
  const int jx = blockIdx.x;
  const int j = jx * 256 + tid;
  const int i0 = blockIdx.y * 8;
  __shared__ float ld[8][BTT][8];
  __shared__ float wredS[4][8];
  if (tid < 8 * BTT) {
    int ii = tid / BTT, bt = tid % BTT;
    const float* pp = pos + ((size_t)bt * NN + i0 + ii) * 3;
    ld[ii][bt][0] = pp[0]; ld[ii][bt][1] = pp[1]; ld[ii][bt][2] = pp[2];
    *(float4*)&ld[ii][bt][4] = *(const float4*)(quat + ((size_t)bt * NN + i0 + ii) * 4);
  }
  __syncthreads();
  float acc[8] = {};
  for (int bt = 0; bt < BTT; ++bt) {
    const float* pj = pos + ((size_t)bt * NN + j) * 3;
    float pjx = pj[0], pjy = pj[1], pjz = pj[2];
    float4 qj = *(const float4*)(quat + ((size_t)bt * NN + j) * 4);
#pragma unroll
    for (int ii = 0; ii < 8; ++ii) {
      float4 pi = *(const float4*)&ld[ii][bt][0];
      float4 qi = *(const float4*)&ld[ii][bt][4];
      float dx = pi.x - pjx, dy = pi.y - pjy, dz = pi.z - pjz;
      float d2 = fmaf(dz, dz, fmaf(dy, dy, dx * dx));
      float dot = fmaf(qi.w, qj.w, fmaf(qi.z, qj.z, fmaf(qi.y, qj.y, qi.x * qj.x)));
      float tq = fmaf(-2.f, fabsf(dot), 2.f);
      acc[ii] += sqrtf(d2) + sqrtf(fmaxf(tq, 0.f));
    }
  }
  const int wv = tid >> 6;
#pragma unroll
  for (int ii = 0; ii < 8; ++ii) {
    float v = exp2f(-acc[ii] * KC);
    w[(size_t)(i0 + ii) * NN + j] = v;
    float s = v;
#pragma unroll
    for (int off = 1; off < 64; off <<= 1) s += __shfl_xor(s, off, 64);
    if ((tid & 63) == 0) wredS[wv][ii] = s;
  }
  __syncthreads();
  if (tid < 8)
    rsp[jx * 1024 + i0 + tid] = wredS[0][tid] + wredS[1][tid] + wredS[2][tid] + wredS[3][tid];
}

// ---------------------------------------------------------------------------
// blocks [0,256) = trajB (memory-bound, first so it overlaps GEMM compute);
// blocks [256,640) = QKV GEMM (128x128 tile).
__global__ __launch_bounds__(256) void qkv_trajB_kernel(const u16* __restrict__ Ab,
                                                        const u16* __restrict__ Wq,
                                                        const u16* __restrict__ Wk,
                                                        const u16* __restrict__ Wv,
                                                        const float* __restrict__ bq,
                                                        const float* __restrict__ bk,
                                                        const float* __restrict__ bv,
                                                        u16* __restrict__ Qb,
                                                        u16* __restrict__ Kb,
                                                        u16* __restrict__ VtT,
                                                        const float* __restrict__ wtr,
                                                        const float* __restrict__ rsp,
                                                        u16* __restrict__ tl) {
  const int tid = threadIdx.x;
  __shared__ __align__(16) u16 As[128 * 32];
  __shared__ __align__(16) u16 Bs[128 * 32];
  if (blockIdx.x < 256) {
    int base = blockIdx.x * 4;
#pragma unroll
    for (int r = 0; r < 4; ++r) {
      int i = base + r;
      float inv = TLC / (rsp[i] + rsp[1024 + i] + rsp[2048 + i] + rsp[3072 + i]);
      float4 w4 = *(const float4*)(wtr + (size_t)i * NN + tid * 4);
      ushort4 o = {f2bf(w4.x * inv), f2bf(w4.y * inv), f2bf(w4.z * inv), f2bf(w4.w * inv)};
      *(ushort4*)(tl + (size_t)i * NN + tid * 4) = o;
    }
    return;
  }
  const int bid = blockIdx.x - 256;
  const int z = bid >> 7;
  const int rem = bid & 127;
  const int bxg = rem & 7, byg = rem >> 3;
  const u16* Wb = z == 0 ? Wq : (z == 1 ? Wk : Wv);
  const float* bias = z == 0 ? bq : (z == 1 ? bk : bv);
  const int w = tid >> 6, l = tid & 63, g = l >> 4, ln = l & 15;
  const int bm = byg << 7, bn = bxg << 7;
  const int srow = w * 16 + (l >> 2);
  const int scol = (l & 3) * 8;
  const u16* Ap0 = Ab + (size_t)(bm + srow) * DD + scol;
  const u16* Ap1 = Ab + (size_t)(bm + 64 + srow) * DD + scol;
  const u16* Bp0 = Wb + (size_t)(bn + srow) * DD + scol;
  const u16* Bp1 = Wb + (size_t)(bn + 64 + srow) * DD + scol;
  u16* dA0 = As + w * 512;
  u16* dA1 = As + 2048 + w * 512;
  u16* dB0 = Bs + w * 512;
  u16* dB1 = Bs + 2048 + w * 512;
  const int mw = (w & 1) * 64, nw = (w >> 1) * 64;
  f32x4 zero4 = {0.f, 0.f, 0.f, 0.f};
  f32x4 acc[4][4];
#pragma unroll
  for (int mt = 0; mt < 4; ++mt)
#pragma unroll
    for (int nt = 0; nt < 4; ++nt) acc[mt][nt] = zero4;
  for (int k0 = 0; k0 < DD; k0 += 32) {
    __syncthreads();
    dma16(Ap0 + k0, dA0); dma16(Ap1 + k0, dA1);
    dma16(Bp0 + k0, dB0); dma16(Bp1 + k0, dB1);
    __syncthreads();
    bf16x8 bfr[4], afr[4];
#pragma unroll
    for (int nt = 0; nt < 4; ++nt)
      bfr[nt] = *(const bf16x8*)&Bs[(nw + nt * 16 + ln) * 32 + g * 8];
#pragma unroll
    for (int mt = 0; mt < 4; ++mt)
      afr[mt] = *(const bf16x8*)&As[(mw + mt * 16 + ln) * 32 + g * 8];
#pragma unroll
    for (int mt = 0; mt < 4; ++mt)
#pragma unroll
      for (int nt = 0; nt < 4; ++nt)
        acc[mt][nt] = __builtin_amdgcn_mfma_f32_16x16x32_bf16(afr[mt], bfr[nt], acc[mt][nt], 0, 0, 0);
  }
#pragma unroll
  for (int nt = 0; nt < 4; ++nt) {
    int n = bn + nw + nt * 16 + ln;
    float bb = bias[n];
    if (z == 2) {
      int row = (((bm >> 10) << 4) + (n >> 6)) * 64 + (n & 63);
#pragma unroll
      for (int mt = 0; mt < 4; ++mt) {
        int tok = (bm & 1023) + mw + mt * 16 + g * 4;
        ushort4 pk = {f2bf(acc[mt][nt][0] + bb), f2bf(acc[mt][nt][1] + bb),
                      f2bf(acc[mt][nt][2] + bb), f2bf(acc[mt][nt][3] + bb)};
        *(ushort4*)(VtT + (size_t)row * NN + tok) = pk;
      }
    } else {
      u16* outp = z == 0 ? Qb : Kb;
#pragma unroll
      for (int mt = 0; mt < 4; ++mt) {
#pragma unroll
        for (int r = 0; r < 4; ++r) {
          int m = bm + mw + mt * 16 + g * 4 + r;
          outp[(size_t)m * DD + n] = f2bf(acc[mt][nt][r] + bb);
        }
      }
    }
  }
}

// ---------------------------------------------------------------------------
// MFMA flash attention, chunk-padded bank-conflict-free LDS (unchanged from R9).
__global__ __launch_bounds__(256) void att_kernel(const u16* __restrict__ Qb,
                                                  const u16* __restrict__ Kb,
                                                  const u16* __restrict__ VtT,
                                                  const u16* __restrict__ tl,
                                                  u16* __restrict__ AOb,
                                                  float* __restrict__ Lv) {
  const int tid = threadIdx.x;
  const int bh = blockIdx.y;
  const int b = bh >> 4, h = bh & 15;
  const int i0 = blockIdx.x << 6;
  const int w = tid >> 6, l = tid & 63, g = l >> 4, ln = l & 15;
  const int wi0 = w * 16;
  __shared__ __align__(16) u16 Qs[8 * CH];
  __shared__ __align__(16) u16 Ks[2][8 * CH];
  __shared__ __align__(16) u16 Vts[2][8 * CH];
  __shared__ __align__(16) u16 Pt[64 * 72];
  __shared__ float lsc[64];
  const int c0 = 2 * w, c1 = 2 * w + 1;
  const int rr = 8 * (l >> 3);
  const int dcol = (l & 7) * 8;
  dma16(Qb + ((size_t)(b * NN) + i0 + c0 + rr) * DD + h * HDD + dcol, Qs + c0 * CH);
  dma16(Qb + ((size_t)(b * NN) + i0 + c1 + rr) * DD + h * HDD + dcol, Qs + c1 * CH);
  const int ig = i0 + wi0 + ln;
  const int lnlo = (ln & 7) * CH;
  const int lnhi = (ln >> 3) * 64;
  f32x4 zero4 = {0.f, 0.f, 0.f, 0.f};
  f32x4 oacc[4];
#pragma unroll
  for (int nt = 0; nt < 4; ++nt) oacc[nt] = zero4;
  float lacc = 0.f;
  for (int j0 = 0; j0 < NN; j0 += 128) {
    __syncthreads();
#pragma unroll
    for (int u = 0; u < 2; ++u) {
      int jb = j0 + u * 64;
      dma16(Kb + ((size_t)(b * NN) + jb + c0 + rr) * DD + h * HDD + dcol, Ks[u] + c0 * CH);
      dma16(Kb + ((size_t)(b * NN) + jb + c1 + rr) * DD + h * HDD + dcol, Ks[u] + c1 * CH);
      dma16(VtT + ((size_t)(bh * 64) + c0 + rr) * NN + jb + dcol, Vts[u] + c0 * CH);
      dma16(VtT + ((size_t)(bh * 64) + c1 + rr) * NN + jb + dcol, Vts[u] + c1 * CH);
    }
    ushort4 tlv[2][4];
#pragma unroll
    for (int u = 0; u < 2; ++u)
#pragma unroll
      for (int jt = 0; jt < 4; ++jt)
        tlv[u][jt] = *(const ushort4*)(tl + (size_t)ig * NN + j0 + u * 64 + jt * 16 + g * 4);
    __syncthreads();
    bf16x8 qf[2];
    qf[0] = *(const bf16x8*)&Qs[lnlo + (2 * w) * 64 + lnhi + g * 8];
    qf[1] = *(const bf16x8*)&Qs[lnlo + (2 * w) * 64 + lnhi + 32 + g * 8];
#pragma unroll
    for (int u = 0; u < 2; ++u) {
      f32x4 sacc[4];
#pragma unroll
      for (int jt = 0; jt < 4; ++jt) {
        sacc[jt] = zero4;
#pragma unroll
        for (int kc = 0; kc < 2; ++kc) {
          bf16x8 af = *(const bf16x8*)&Ks[u][lnlo + (2 * jt) * 64 + lnhi + kc * 32 + g * 8];
          sacc[jt] = __builtin_amdgcn_mfma_f32_16x16x32_bf16(af, qf[kc], sacc[jt], 0, 0, 0);
        }
      }
#pragma unroll
      for (int jt = 0; jt < 4; ++jt) {
        float e0 = exp2f(sacc[jt][0] * C1 + b2f(tlv[u][jt].x));
        float e1 = exp2f(sacc[jt][1] * C1 + b2f(tlv[u][jt].y));
        float e2 = exp2f(sacc[jt][2] * C1 + b2f(tlv[u][jt].z));
        float e3 = exp2f(sacc[jt][3] * C1 + b2f(tlv[u][jt].w));
        lacc += (e0 + e1) + (e2 + e3);
        ushort4 pk = {f2bf(e0), f2bf(e1), f2bf(e2), f2bf(e3)};
        *(ushort4*)(Pt + (wi0 + ln) * 72 + jt * 16 + g * 4) = pk;
      }
      bf16x8 pf[2];
      pf[0] = *(const bf16x8*)&Pt[(wi0 + ln) * 72 + g * 8];
      pf[1] = *(const bf16x8*)&Pt[(wi0 + ln) * 72 + 32 + g * 8];
#pragma unroll
      for (int nt = 0; nt < 4; ++nt) {
#pragma unroll
        for (int kc = 0; kc < 2; ++kc) {
          bf16x8 vf = *(const bf16x8*)&Vts[u][lnlo + (2 * nt) * 64 + lnhi + kc * 32 + g * 8];
          oacc[nt] = __builtin_amdgcn_mfma_f32_16x16x32_bf16(pf[kc], vf, oacc[nt], 0, 0, 0);
        }
      }
    }
  }
  lacc += __shfl_xor(lacc, 16, 64);
  lacc += __shfl_xor(lacc, 32, 64);
  if (g == 0) {
    Lv[(size_t)bh * NN + i0 + wi0 + ln] = lacc;
    lsc[wi0 + ln] = 1.f / lacc;
  }
  __syncthreads();
#pragma unroll
  for (int nt = 0; nt < 4; ++nt) {
    int d = nt * 16 + ln;
#pragma unroll
    for (int r = 0; r < 4; ++r) {
      int i = wi0 + g * 4 + r;
      float v = oacc[nt][r] * lsc[i];
      AOb[((size_t)(b * NN) + i0 + i) * DD + h * HDD + d] = f2bf(v);
    }
  }
}

// ---------------------------------------------------------------------------
// Entropy, STANDALONE (512 blocks = exactly full 2/CU residency; no union-LDS
// serialization with gemm_o -- R9 postmortem). Chunk-padded conflict-free LDS.
__global__ __launch_bounds__(256) void ent_kernel(const u16* __restrict__ Qb,
                                                  const u16* __restrict__ Kb,
                                                  const u16* __restrict__ tl,
                                                  const float* __restrict__ Lv,
                                                  float* __restrict__ Hp) {
  const int tid = threadIdx.x;
  const int jx = blockIdx.x & 15;
  const int iy = (blockIdx.x >> 4) & 15;
  const int b = blockIdx.x >> 8;
  const int j0 = jx << 6, i0 = iy << 6;
  const int w = tid >> 6, l = tid & 63, g = l >> 4, ln = l & 15;
  const int wi0 = w * 16;
  __shared__ __align__(16) u16 Qs[32 * CH];
  __shared__ __align__(16) u16 Ks[32 * CH];
  __shared__ float linv[NHH * 64];
#pragma unroll
  for (int rep = 0; rep < 4; ++rep) {
    int idx = tid + (rep << 8);
    int hh = idx >> 6, ii = idx & 63;
    linv[hh * 64 + ii] = 1.f / Lv[((size_t)((b << 4) + hh)) * NN + i0 + ii];
  }
  const int rlo = l >> 5;
  const int scol = (l & 31) * 8;
  const int ig = i0 + wi0 + ln;
  const int elo = (ln >> 1) * CH;
  const int ehi = (ln & 1) * 256;
  ushort4 tlv[4];
#pragma unroll
  for (int jt = 0; jt < 4; ++jt)
    tlv[jt] = *(const ushort4*)(tl + (size_t)ig * NN + j0 + jt * 16 + g * 4);
  float P[4][4] = {};
  f32x4 zero4 = {0.f, 0.f, 0.f, 0.f};
  for (int hb = 0; hb < 4; ++hb) {
    __syncthreads();
#pragma unroll
    for (int cc = 0; cc < 8; ++cc) {
      int c = w * 8 + cc;
      dma16(Qb + ((size_t)(b * NN) + i0 + 2 * c + rlo) * DD + hb * 256 + scol, Qs + c * CH);
      dma16(Kb + ((size_t)(b * NN) + j0 + 2 * c + rlo) * DD + hb * 256 + scol, Ks + c * CH);
    }
    __syncthreads();
#pragma unroll
    for (int hl = 0; hl < 4; ++hl) {
      float li = linv[(hb * 4 + hl) * 64 + wi0 + ln];
      bf16x8 qf[2];
      qf[0] = *(const bf16x8*)&Qs[(w * 8) * CH + elo + ehi + hl * 64 + g * 8];
      qf[1] = *(const bf16x8*)&Qs[(w * 8) * CH + elo + ehi + hl * 64 + 32 + g * 8];
#pragma unroll
      for (int jt = 0; jt < 4; ++jt) {
        f32x4 sacc = zero4;
#pragma unroll
        for (int kc = 0; kc < 2; ++kc) {
          bf16x8 af = *(const bf16x8*)&Ks[(jt * 8) * CH + elo + ehi + hl * 64 + kc * 32 + g * 8];
          sacc = __builtin_amdgcn_mfma_f32_16x16x32_bf16(af, qf[kc], sacc, 0, 0, 0);
        }
        P[jt][0] += exp2f(sacc[0] * C1 + b2f(tlv[jt].x)) * li;
        P[jt][1] += exp2f(sacc[1] * C1 + b2f(tlv[jt].y)) * li;
        P[jt][2] += exp2f(sacc[2] * C1 + b2f(tlv[jt].z)) * li;
        P[jt][3] += exp2f(sacc[3] * C1 + b2f(tlv[jt].w)) * li;
      }
    }
  }
  float hs = 0.f;
#pragma unroll
  for (int jt = 0; jt < 4; ++jt) {
#pragma unroll
    for (int r = 0; r < 4; ++r) {
      float p = fmaxf(P[jt][r] * (1.f / NHH), 1e-10f);
      hs -= p * logf(p);
    }
  }
  hs += __shfl_xor(hs, 16, 64);
  hs += __shfl_xor(hs, 32, 64);
  if (g == 0) Hp[jx * 2048 + (size_t)b * NN + i0 + wi0 + ln] = hs;
}

// ---------------------------------------------------------------------------
// blocks [0,128) = output projection GEMM (16 KB LDS only -> high occupancy);
// blocks [128,136) = certainty update (depends on ent = previous launch).
__global__ __launch_bounds__(256) void gemmo_cert_kernel(const u16* __restrict__ Ab,
                                                         const u16* __restrict__ Wb,
                                                         const float* __restrict__ bias,
                                                         float* __restrict__ C,
                                                         const float* __restrict__ Hp,
                                                         const float* __restrict__ cert,
                                                         float* __restrict__ outc) {
  const int tid = threadIdx.x;
  __shared__ __align__(16) u16 As[128 * 32];
  __shared__ __align__(16) u16 Bs[128 * 32];
  if (blockIdx.x >= 128) {
    int idx = (blockIdx.x - 128) * 256 + tid;
    float H = 0.f;
#pragma unroll
    for (int jt = 0; jt < 16; ++jt) H += Hp[jt * 2048 + idx];
    float sg = 1.f / (1.f + expf(H - HMAXL));
    outc[idx] = fmaxf(cert[idx], sg);
    return;
  }
  const int bxg = blockIdx.x & 7, byg = blockIdx.x >> 3;
  const int w = tid >> 6, l = tid & 63, g = l >> 4, ln = l & 15;
  const int bm = byg << 7, bn = bxg << 7;
  const int srow = w * 16 + (l >> 2);
  const int scol = (l & 3) * 8;
  const u16* Ap0 = Ab + (size_t)(bm + srow) * DD + scol;
  const u16* Ap1 = Ab + (size_t)(bm + 64 + srow) * DD + scol;
  const u16* Bp0 = Wb + (size_t)(bn + srow) * DD + scol;
  const u16* Bp1 = Wb + (size_t)(bn + 64 + srow) * DD + scol;
  u16* dA0 = As + w * 512;
  u16* dA1 = As + 2048 + w * 512;
  u16* dB0 = Bs + w * 512;
  u16* dB1 = Bs + 2048 + w * 512;
  const int mw = (w & 1) * 64, nw = (w >> 1) * 64;
  f32x4 zero4 = {0.f, 0.f, 0.f, 0.f};
  f32x4 acc[4][4];
#pragma unroll
  for (int mt = 0; mt < 4; ++mt)
#pragma unroll
    for (int nt = 0; nt < 4; ++nt) acc[mt][nt] = zero4;
  for (int k0 = 0; k0 < DD; k0 += 32) {
    __syncthreads();
    dma16(Ap0 + k0, dA0); dma16(Ap1 + k0, dA1);
    dma16(Bp0 + k0, dB0); dma16(Bp1 + k0, dB1);
    __syncthreads();
    bf16x8 bfr[4], afr[4];
#pragma unroll
    for (int nt = 0; nt < 4; ++nt)
      bfr[nt] = *(const bf16x8*)&Bs[(nw + nt * 16 + ln) * 32 + g * 8];
#pragma unroll
    for (int mt = 0; mt < 4; ++mt)
      afr[mt] = *(const bf16x8*)&As[(mw + mt * 16 + ln) * 32 + g * 8];
#pragma unroll
    for (int mt = 0; mt < 4; ++mt)
#pragma unroll
      for (int nt = 0; nt < 4; ++nt)
        acc[mt][nt] = __builtin_amdgcn_mfma_f32_16x16x32_bf16(afr[mt], bfr[nt], acc[mt][nt], 0, 0, 0);
  }
#pragma unroll
  for (int nt = 0; nt < 4; ++nt) {
    int n = bn + nw + nt * 16 + ln;
    float bb = bias[n];
#pragma unroll
    for (int mt = 0; mt < 4; ++mt) {
#pragma unroll
      for (int r = 0; r < 4; ++r) {
        int m = bm + mw + mt * 16 + g * 4 + r;
        C[(size_t)m * DD + n] = acc[mt][nt][r] + bb;
      }
    }
  }
}

// ---------------------------------------------------------------------------
extern "C" void kernel_launch(void* const* d_in, const int* in_sizes, int n_in,
                              void* d_out, int out_size, void* d_ws, size_t ws_size,
                              hipStream_t stream) {
  const float* data      = (const float*)d_in[0];
  const float* traj_pos  = (const float*)d_in[1];
  const float* traj_quat = (const float*)d_in[2];
  const float* certainty = (const float*)d_in[3];
  const float* Wq = (const float*)d_in[4];
  const float* bq = (const float*)d_in[5];
  const float* Wk = (const float*)d_in[6];
  const float* bk = (const float*)d_in[7];
  const float* Wv = (const float*)d_in[8];
  const float* bv = (const float*)d_in[9];
  const float* Wo = (const float*)d_in[10];
  const float* bo = (const float*)d_in[11];

  float* ws = (float*)d_ws;
  float* wtr  = ws + TRAJ_OFF;
  u16* tl    = (u16*)(ws + TL_OFF);
  u16* datab = (u16*)(ws + DATAB_OFF);
  u16* wqb   = (u16*)(ws + WQB_OFF);
  u16* wkb   = (u16*)(ws + WKB_OFF);
  u16* wvb   = (u16*)(ws + WVB_OFF);
  u16* wob   = (u16*)(ws + WOB_OFF);
  u16* Qb    = (u16*)(ws + QB_OFF);
  u16* Kb    = (u16*)(ws + KB_OFF);
  u16* VtT   = (u16*)(ws + VT_OFF);
  u16* AOb   = (u16*)(ws + AOB_OFF);
  float* Lv   = ws + LV_OFF;
  float* Hp   = ws + HPART_OFF;
  float* rsp  = ws + RSP_OFF;
  float* out  = (float*)d_out;
  float* outc = out + (size_t)NB * NN * DD;

  conv_kernel<<<dim3(1024, 6), 256, 0, stream>>>(data, Wq, Wk, Wv, Wo,
                                                 datab, wqb, wkb, wvb, wob);
  trajA_kernel<<<dim3(4, 128), 256, 0, stream>>>(traj_pos, traj_quat, wtr, rsp);
  qkv_trajB_kernel<<<640, 256, 0, stream>>>(datab, wqb, wkb, wvb, bq, bk, bv,
                                            Qb, Kb, VtT, wtr, rsp, tl);
  att_kernel<<<dim3(NN / 64, NB * NHH), 256, 0, stream>>>(Qb, Kb, VtT, tl, AOb, Lv);
  ent_kernel<<<512, 256, 0, stream>>>(Qb, Kb, tl, Lv, Hp);
  gemmo_cert_kernel<<<136, 256, 0, stream>>>(AOb, wob, bo, out, Hp, certainty, outc);
}